// Round 1
// baseline (10140.642 us; speedup 1.0000x reference)
//
#include <hip/hip_runtime.h>

#define B_   2
#define S_   2048
#define D_   512
#define H_   8
#define DK_  64
#define DFF_ 2048
#define L_   2
#define BS_  (B_*S_)   // 4096

// ---------------- embedding gather ----------------
__global__ __launch_bounds__(128) void embed_kernel(const int* __restrict__ tokens,
                                                    const float* __restrict__ embed,
                                                    float* __restrict__ zr) {
  int row = blockIdx.x;                      // 0..4095  (b*S+s)
  int tok = tokens[row];
  const float4* src = (const float4*)(embed + (size_t)tok * D_);
  float4* dst = (float4*)(zr + (size_t)row * D_);
  dst[threadIdx.x] = src[threadIdx.x];       // 128 threads * float4 = 512 floats
}

// ---------------- positional imaginary part: zi[s,2j]=zi[s,2j+1]=sin(s*freq_j) ----------------
__global__ __launch_bounds__(128) void zi_kernel(float* __restrict__ zi) {
  int s = blockIdx.x;
  int j0 = threadIdx.x * 2;                  // 2 freq indices per thread (256 total)
  const double LN1E4 = 9.210340371976184;    // ln(10000)
  #pragma unroll
  for (int t = 0; t < 2; ++t) {
    int jj = j0 + t;
    double freq = exp(-((double)jj / 256.0) * LN1E4);   // 10000^{-2j/D}
    float val = (float)sin((double)s * freq);           // GAMMA = 1
    zi[(size_t)s * D_ + 2*jj]     = val;
    zi[(size_t)s * D_ + 2*jj + 1] = val;
  }
}

// ---------------- fp32 tiled GEMM: C[M,N] = A[M,K] @ W[K,N] (+bias) (+relu) ----------------
// M,N multiples of 64; K multiple of 16.
__global__ __launch_bounds__(256) void gemm64(const float* __restrict__ A,
                                              const float* __restrict__ W,
                                              const float* __restrict__ bias,
                                              float* __restrict__ Cmat,
                                              int M, int N, int K, int relu) {
  __shared__ float As[16][68];   // transposed: As[k][m], pad 4 keeps float4 alignment
  __shared__ float Bs[16][64];   // natural: Bs[k][n]
  const int tid = threadIdx.x;
  const int m0 = blockIdx.y * 64, n0 = blockIdx.x * 64;
  const int tx = tid & 15, ty = tid >> 4;

  float acc[4][4];
  #pragma unroll
  for (int i = 0; i < 4; ++i)
    #pragma unroll
    for (int j = 0; j < 4; ++j) acc[i][j] = 0.f;

  const int am  = tid >> 2;            // 0..63 (A tile row)
  const int ak  = (tid & 3) * 4;       // 0,4,8,12 (k offset)
  const int brow = tid >> 4;           // 0..15 (B tile k row)
  const int bcol = (tid & 15) * 4;     // 0..60

  for (int k0 = 0; k0 < K; k0 += 16) {
    float4 av = *(const float4*)(A + (size_t)(m0 + am) * K + k0 + ak);
    float4 bv = *(const float4*)(W + (size_t)(k0 + brow) * N + n0 + bcol);
    As[ak + 0][am] = av.x;
    As[ak + 1][am] = av.y;
    As[ak + 2][am] = av.z;
    As[ak + 3][am] = av.w;
    *(float4*)&Bs[brow][bcol] = bv;
    __syncthreads();
    #pragma unroll
    for (int k = 0; k < 16; ++k) {
      float4 a = *(const float4*)&As[k][ty * 4];
      float4 b = *(const float4*)&Bs[k][tx * 4];
      float a_[4] = {a.x, a.y, a.z, a.w};
      float b_[4] = {b.x, b.y, b.z, b.w};
      #pragma unroll
      for (int i = 0; i < 4; ++i)
        #pragma unroll
        for (int j = 0; j < 4; ++j)
          acc[i][j] += a_[i] * b_[j];
    }
    __syncthreads();
  }

  const int ccol = n0 + tx * 4;
  float4 badd = make_float4(0.f, 0.f, 0.f, 0.f);
  if (bias) badd = *(const float4*)(bias + ccol);
  #pragma unroll
  for (int i = 0; i < 4; ++i) {
    int row = m0 + ty * 4 + i;
    float4 r;
    r.x = acc[i][0] + badd.x;
    r.y = acc[i][1] + badd.y;
    r.z = acc[i][2] + badd.z;
    r.w = acc[i][3] + badd.w;
    if (relu) {
      r.x = fmaxf(r.x, 0.f); r.y = fmaxf(r.y, 0.f);
      r.z = fmaxf(r.z, 0.f); r.w = fmaxf(r.w, 0.f);
    }
    *(float4*)(Cmat + (size_t)row * N + ccol) = r;
  }
}

// ---------------- C[b*S+s, :] += sign * T[s, :]  (broadcast zi-projection over batch) ----------------
__global__ __launch_bounds__(256) void combine_kernel(float* __restrict__ C,
                                                      const float* __restrict__ T,
                                                      float sign) {
  const int total = BS_ * (D_ / 4);          // float4 count
  for (int i = blockIdx.x * blockDim.x + threadIdx.x; i < total;
       i += gridDim.x * blockDim.x) {
    int r = i >> 7;                          // / (D_/4)
    int c = (i & 127) * 4;
    float4 t = *(const float4*)(T + (size_t)(r & (S_ - 1)) * D_ + c);
    float4* cp = (float4*)(C + (size_t)r * D_ + c);
    float4 v = *cp;
    v.x += sign * t.x; v.y += sign * t.y; v.z += sign * t.z; v.w += sign * t.w;
    *cp = v;
  }
}

// ---------------- complex-hybrid flash attention ----------------
// grid: (S/32, B*H); block 256 = 4 waves. Each wave owns 8 q rows.
__global__ __launch_bounds__(256) void attn_kernel(const float* __restrict__ QR,
                                                   const float* __restrict__ QI,
                                                   const float* __restrict__ KR,
                                                   const float* __restrict__ KI,
                                                   const float* __restrict__ VV,
                                                   float* __restrict__ CTX) {
  const int bh = blockIdx.y;                 // b*H + h
  const int b = bh >> 3, h = bh & 7;
  const int q0 = blockIdx.x * 32;
  const int tid = threadIdx.x;
  const int lane = tid & 63, wv = tid >> 6;

  __shared__ float q_r[32][64];
  __shared__ float q_i[32][64];
  __shared__ float k_rt[64][65];             // transposed [d][j]
  __shared__ float k_it[64][65];
  __shared__ float v_s[64][64];              // natural [j][d]

  const size_t base = ((size_t)b * S_) * D_ + (size_t)h * DK_;

  // stage Q tile (32 rows x 64 cols x 2)
  #pragma unroll
  for (int i = 0; i < 2; ++i) {
    int idx = tid + i * 256;                 // 0..511
    int r = idx >> 4;
    int c4 = (idx & 15) * 4;
    *(float4*)&q_r[r][c4] = *(const float4*)(QR + base + (size_t)(q0 + r) * D_ + c4);
    *(float4*)&q_i[r][c4] = *(const float4*)(QI + base + (size_t)(q0 + r) * D_ + c4);
  }

  float m_s[8], l_s[8], o_s[8];
  #pragma unroll
  for (int r = 0; r < 8; ++r) { m_s[r] = -1e30f; l_s[r] = 0.f; o_s[r] = 0.f; }

  for (int c0 = 0; c0 < S_; c0 += 64) {
    __syncthreads();                         // covers Q stage (iter 0) + prev-chunk reads
    #pragma unroll
    for (int i = 0; i < 4; ++i) {
      int idx = tid + i * 256;               // 0..1023
      int j = idx >> 4;                      // 0..63
      int c4 = (idx & 15) * 4;
      float4 kr4 = *(const float4*)(KR + base + (size_t)(c0 + j) * D_ + c4);
      float4 ki4 = *(const float4*)(KI + base + (size_t)(c0 + j) * D_ + c4);
      float4 v4  = *(const float4*)(VV + base + (size_t)(c0 + j) * D_ + c4);
      k_rt[c4 + 0][j] = kr4.x; k_rt[c4 + 1][j] = kr4.y;
      k_rt[c4 + 2][j] = kr4.z; k_rt[c4 + 3][j] = kr4.w;
      k_it[c4 + 0][j] = ki4.x; k_it[c4 + 1][j] = ki4.y;
      k_it[c4 + 2][j] = ki4.z; k_it[c4 + 3][j] = ki4.w;
      *(float4*)&v_s[j][c4] = v4;
    }
    __syncthreads();

    for (int rr = 0; rr < 8; ++rr) {
      const int r = wv * 8 + rr;
      float sr = 0.f, si = 0.f;
      #pragma unroll
      for (int d = 0; d < 64; ++d) {
        float krv = k_rt[d][lane];
        float kiv = k_it[d][lane];
        float qrv = q_r[r][d];               // LDS broadcast
        float qiv = q_i[r][d];
        sr += qrv * krv + qiv * kiv;
        si += qiv * krv - qrv * kiv;
      }
      sr *= 0.125f; si *= 0.125f;            // SCALE = 1/sqrt(64)
      float mag = sqrtf(sr * sr + si * si);
      float ph = (mag == 0.f) ? 1.f : sr / mag;
      float sc = (mag + 0.3f * ph) * 0.125f; // (mag + ALPHA*cos)/sqrt(dk)

      float mx = sc;
      mx = fmaxf(mx, __shfl_xor(mx, 32)); mx = fmaxf(mx, __shfl_xor(mx, 16));
      mx = fmaxf(mx, __shfl_xor(mx, 8));  mx = fmaxf(mx, __shfl_xor(mx, 4));
      mx = fmaxf(mx, __shfl_xor(mx, 2));  mx = fmaxf(mx, __shfl_xor(mx, 1));
      float newm = fmaxf(m_s[rr], mx);
      float alpha = __expf(m_s[rr] - newm);
      float p = __expf(sc - newm);
      float ps = p;
      ps += __shfl_xor(ps, 32); ps += __shfl_xor(ps, 16); ps += __shfl_xor(ps, 8);
      ps += __shfl_xor(ps, 4);  ps += __shfl_xor(ps, 2);  ps += __shfl_xor(ps, 1);
      l_s[rr] = l_s[rr] * alpha + ps;
      m_s[rr] = newm;

      float o = o_s[rr] * alpha;
      #pragma unroll
      for (int j = 0; j < 64; ++j) {
        o += __shfl(p, j) * v_s[j][lane];    // readlane broadcast of p_j
      }
      o_s[rr] = o;
    }
  }

  #pragma unroll
  for (int rr = 0; rr < 8; ++rr) {
    int r = wv * 8 + rr;
    CTX[base + (size_t)(q0 + r) * D_ + lane] = o_s[rr] / l_s[rr];
  }
}

// ---------------- layernorm: Out[row] = LN(X[row] + R[row]) * g + be ----------------
__global__ __launch_bounds__(256) void ln_kernel(const float* __restrict__ X,
                                                 const float* __restrict__ R,
                                                 const float* __restrict__ g,
                                                 const float* __restrict__ be,
                                                 float* __restrict__ Out) {
  const int lane = threadIdx.x & 63;
  const int wv = threadIdx.x >> 6;
  const int row = blockIdx.x * 4 + wv;
  const float* xp = X + (size_t)row * D_;
  const float* rp = R + (size_t)row * D_;
  float x[8];
  float s = 0.f;
  #pragma unroll
  for (int i = 0; i < 8; ++i) {
    int d = i * 64 + lane;
    x[i] = xp[d] + rp[d];
    s += x[i];
  }
  s += __shfl_xor(s, 32); s += __shfl_xor(s, 16); s += __shfl_xor(s, 8);
  s += __shfl_xor(s, 4);  s += __shfl_xor(s, 2);  s += __shfl_xor(s, 1);
  float mu = s * (1.f / 512.f);
  float vs = 0.f;
  #pragma unroll
  for (int i = 0; i < 8; ++i) { float d = x[i] - mu; vs += d * d; }
  vs += __shfl_xor(vs, 32); vs += __shfl_xor(vs, 16); vs += __shfl_xor(vs, 8);
  vs += __shfl_xor(vs, 4);  vs += __shfl_xor(vs, 2);  vs += __shfl_xor(vs, 1);
  float rstd = rsqrtf(vs * (1.f / 512.f) + 1e-5f);
  float* op = Out + (size_t)row * D_;
  #pragma unroll
  for (int i = 0; i < 8; ++i) {
    int d = i * 64 + lane;
    op[d] = (x[i] - mu) * rstd * g[d] + be[d];
  }
}

// ---------------- head: out[r,c] = Z[r,:] @ hw[:,c] + hb[c], C=2 ----------------
__global__ __launch_bounds__(256) void head_kernel(const float* __restrict__ Z,
                                                   const float* __restrict__ hw,
                                                   const float* __restrict__ hb,
                                                   float* __restrict__ out) {
  const int lane = threadIdx.x & 63;
  const int wv = threadIdx.x >> 6;
  const int row = blockIdx.x * 4 + wv;
  const float* zp = Z + (size_t)row * D_;
  float a0 = 0.f, a1 = 0.f;
  #pragma unroll
  for (int i = 0; i < 8; ++i) {
    int d = i * 64 + lane;
    float z = zp[d];
    a0 += z * hw[d * 2];
    a1 += z * hw[d * 2 + 1];
  }
  a0 += __shfl_xor(a0, 32); a0 += __shfl_xor(a0, 16); a0 += __shfl_xor(a0, 8);
  a0 += __shfl_xor(a0, 4);  a0 += __shfl_xor(a0, 2);  a0 += __shfl_xor(a0, 1);
  a1 += __shfl_xor(a1, 32); a1 += __shfl_xor(a1, 16); a1 += __shfl_xor(a1, 8);
  a1 += __shfl_xor(a1, 4);  a1 += __shfl_xor(a1, 2);  a1 += __shfl_xor(a1, 1);
  if (lane == 0) {
    out[row * 2]     = a0 + hb[0];
    out[row * 2 + 1] = a1 + hb[1];
  }
}

extern "C" void kernel_launch(void* const* d_in, const int* in_sizes, int n_in,
                              void* d_out, int out_size, void* d_ws, size_t ws_size,
                              hipStream_t stream) {
  const int*   tokens = (const int*)  d_in[0];
  const float* embed  = (const float*)d_in[1];
  const float* Wqr = (const float*)d_in[2];
  const float* Wqi = (const float*)d_in[3];
  const float* Wkr = (const float*)d_in[4];
  const float* Wki = (const float*)d_in[5];
  const float* Wv  = (const float*)d_in[6];
  const float* Wo  = (const float*)d_in[7];
  const float* bo  = (const float*)d_in[8];
  const float* W1  = (const float*)d_in[9];
  const float* b1  = (const float*)d_in[10];
  const float* W2  = (const float*)d_in[11];
  const float* b2  = (const float*)d_in[12];
  const float* g1  = (const float*)d_in[13];
  const float* be1 = (const float*)d_in[14];
  const float* g2  = (const float*)d_in[15];
  const float* be2 = (const float*)d_in[16];
  const float* hw  = (const float*)d_in[17];
  const float* hb  = (const float*)d_in[18];
  float* out = (float*)d_out;

  float* ws = (float*)d_ws;
  const size_t NBD = (size_t)BS_ * D_;       // 2M floats
  float* zr   = ws;  ws += NBD;
  float* zi   = ws;  ws += (size_t)S_ * D_;
  float* qr   = ws;  ws += NBD;              // ff aliases qr..ki (4*NBD = BS_*DFF_)
  float* qi   = ws;  ws += NBD;
  float* kr   = ws;  ws += NBD;
  float* ki   = ws;  ws += NBD;
  float* vv   = ws;  ws += NBD;
  float* ctx  = ws;  ws += NBD;
  float* hbuf = ws;  ws += NBD;
  float* z1   = ws;  ws += NBD;
  float* tmp  = ws;  ws += (size_t)S_ * D_;
  float* ff   = qr;                           // [BS_, DFF_] reuses dead q/k space

  embed_kernel<<<BS_, 128, 0, stream>>>(tokens, embed, zr);
  zi_kernel<<<S_, 128, 0, stream>>>(zi);

  for (int l = 0; l < L_; ++l) {
    const float* wqr = Wqr + (size_t)l * D_ * D_;
    const float* wqi = Wqi + (size_t)l * D_ * D_;
    const float* wkr = Wkr + (size_t)l * D_ * D_;
    const float* wki = Wki + (size_t)l * D_ * D_;
    const float* wv  = Wv  + (size_t)l * D_ * D_;
    const float* wo  = Wo  + (size_t)l * D_ * D_;
    const float* w1  = W1  + (size_t)l * D_ * DFF_;
    const float* w2  = W2  + (size_t)l * DFF_ * D_;

    dim3 g512(D_ / 64, BS_ / 64);            // (8, 64)
    gemm64<<<g512, 256, 0, stream>>>(zr, wqr, nullptr, qr, BS_, D_, D_, 0);
    gemm64<<<g512, 256, 0, stream>>>(zr, wqi, nullptr, qi, BS_, D_, D_, 0);
    gemm64<<<g512, 256, 0, stream>>>(zr, wkr, nullptr, kr, BS_, D_, D_, 0);
    gemm64<<<g512, 256, 0, stream>>>(zr, wki, nullptr, ki, BS_, D_, D_, 0);
    gemm64<<<g512, 256, 0, stream>>>(zr, wv,  nullptr, vv, BS_, D_, D_, 0);

    if (l == 0) {                            // zi terms exist only in layer 0
      dim3 gHalf(D_ / 64, S_ / 64);          // (8, 32)
      gemm64<<<gHalf, 256, 0, stream>>>(zi, wqi, nullptr, tmp, S_, D_, D_, 0);
      combine_kernel<<<512, 256, 0, stream>>>(qr, tmp, -1.f);
      gemm64<<<gHalf, 256, 0, stream>>>(zi, wqr, nullptr, tmp, S_, D_, D_, 0);
      combine_kernel<<<512, 256, 0, stream>>>(qi, tmp, +1.f);
      gemm64<<<gHalf, 256, 0, stream>>>(zi, wki, nullptr, tmp, S_, D_, D_, 0);
      combine_kernel<<<512, 256, 0, stream>>>(kr, tmp, -1.f);
      gemm64<<<gHalf, 256, 0, stream>>>(zi, wkr, nullptr, tmp, S_, D_, D_, 0);
      combine_kernel<<<512, 256, 0, stream>>>(ki, tmp, +1.f);
    }

    dim3 ga(S_ / 32, B_ * H_);               // (64, 16)
    attn_kernel<<<ga, 256, 0, stream>>>(qr, qi, kr, ki, vv, ctx);

    gemm64<<<g512, 256, 0, stream>>>(ctx, wo, bo + l * D_, hbuf, BS_, D_, D_, 0);
    ln_kernel<<<BS_ / 4, 256, 0, stream>>>(zr, hbuf, g1 + l * D_, be1 + l * D_, z1);

    dim3 gff1(DFF_ / 64, BS_ / 64);          // (32, 64)
    gemm64<<<gff1, 256, 0, stream>>>(z1, w1, b1 + l * DFF_, ff, BS_, DFF_, D_, 1);
    gemm64<<<g512, 256, 0, stream>>>(ff, w2, b2 + l * D_, hbuf, BS_, D_, DFF_, 0);
    ln_kernel<<<BS_ / 4, 256, 0, stream>>>(z1, hbuf, g2 + l * D_, be2 + l * D_, zr);
  }

  head_kernel<<<BS_ / 4, 256, 0, stream>>>(zr, hw, hb, out);
}

// Round 2
// 1625.413 us; speedup vs baseline: 6.2388x; 6.2388x over previous
//
#include <hip/hip_runtime.h>

#define B_   2
#define S_   2048
#define D_   512
#define H_   8
#define DK_  64
#define DFF_ 2048
#define L_   2
#define BS_  (B_*S_)   // 4096

typedef __attribute__((ext_vector_type(8))) short bfrag;   // 8 bf16 in 4 VGPRs
typedef __attribute__((ext_vector_type(4))) float facc;    // 4 fp32 acc

__device__ __forceinline__ unsigned short f2b(float f) {
  union { float f; unsigned int u; } c; c.f = f;
  unsigned int u = c.u;
  u += 0x7fffu + ((u >> 16) & 1);    // round-to-nearest-even
  return (unsigned short)(u >> 16);
}

// ---------------- embedding gather ----------------
__global__ __launch_bounds__(128) void embed_kernel(const int* __restrict__ tokens,
                                                    const float* __restrict__ embed,
                                                    float* __restrict__ zr) {
  int row = blockIdx.x;
  int tok = tokens[row];
  const float4* src = (const float4*)(embed + (size_t)tok * D_);
  float4* dst = (float4*)(zr + (size_t)row * D_);
  dst[threadIdx.x] = src[threadIdx.x];
}

// ---------------- positional imaginary part ----------------
__global__ __launch_bounds__(128) void zi_kernel(float* __restrict__ zi) {
  int s = blockIdx.x;
  int j0 = threadIdx.x * 2;
  const double LN1E4 = 9.210340371976184;
  #pragma unroll
  for (int t = 0; t < 2; ++t) {
    int jj = j0 + t;
    double freq = exp(-((double)jj / 256.0) * LN1E4);
    float val = (float)sin((double)s * freq);
    zi[(size_t)s * D_ + 2*jj]     = val;
    zi[(size_t)s * D_ + 2*jj + 1] = val;
  }
}

// ---------------- fp32 tiled GEMM (unchanged) ----------------
__global__ __launch_bounds__(256) void gemm64(const float* __restrict__ A,
                                              const float* __restrict__ W,
                                              const float* __restrict__ bias,
                                              float* __restrict__ Cmat,
                                              int M, int N, int K, int relu) {
  __shared__ float As[16][68];
  __shared__ float Bs[16][64];
  const int tid = threadIdx.x;
  const int m0 = blockIdx.y * 64, n0 = blockIdx.x * 64;
  const int tx = tid & 15, ty = tid >> 4;

  float acc[4][4];
  #pragma unroll
  for (int i = 0; i < 4; ++i)
    #pragma unroll
    for (int j = 0; j < 4; ++j) acc[i][j] = 0.f;

  const int am  = tid >> 2;
  const int ak  = (tid & 3) * 4;
  const int brow = tid >> 4;
  const int bcol = (tid & 15) * 4;

  for (int k0 = 0; k0 < K; k0 += 16) {
    float4 av = *(const float4*)(A + (size_t)(m0 + am) * K + k0 + ak);
    float4 bv = *(const float4*)(W + (size_t)(k0 + brow) * N + n0 + bcol);
    As[ak + 0][am] = av.x;
    As[ak + 1][am] = av.y;
    As[ak + 2][am] = av.z;
    As[ak + 3][am] = av.w;
    *(float4*)&Bs[brow][bcol] = bv;
    __syncthreads();
    #pragma unroll
    for (int k = 0; k < 16; ++k) {
      float4 a = *(const float4*)&As[k][ty * 4];
      float4 b = *(const float4*)&Bs[k][tx * 4];
      float a_[4] = {a.x, a.y, a.z, a.w};
      float b_[4] = {b.x, b.y, b.z, b.w};
      #pragma unroll
      for (int i = 0; i < 4; ++i)
        #pragma unroll
        for (int j = 0; j < 4; ++j)
          acc[i][j] += a_[i] * b_[j];
    }
    __syncthreads();
  }

  const int ccol = n0 + tx * 4;
  float4 badd = make_float4(0.f, 0.f, 0.f, 0.f);
  if (bias) badd = *(const float4*)(bias + ccol);
  #pragma unroll
  for (int i = 0; i < 4; ++i) {
    int row = m0 + ty * 4 + i;
    float4 r;
    r.x = acc[i][0] + badd.x;
    r.y = acc[i][1] + badd.y;
    r.z = acc[i][2] + badd.z;
    r.w = acc[i][3] + badd.w;
    if (relu) {
      r.x = fmaxf(r.x, 0.f); r.y = fmaxf(r.y, 0.f);
      r.z = fmaxf(r.z, 0.f); r.w = fmaxf(r.w, 0.f);
    }
    *(float4*)(Cmat + (size_t)row * N + ccol) = r;
  }
}

// ---------------- broadcast zi-projection over batch ----------------
__global__ __launch_bounds__(256) void combine_kernel(float* __restrict__ C,
                                                      const float* __restrict__ T,
                                                      float sign) {
  const int total = BS_ * (D_ / 4);
  for (int i = blockIdx.x * blockDim.x + threadIdx.x; i < total;
       i += gridDim.x * blockDim.x) {
    int r = i >> 7;
    int c = (i & 127) * 4;
    float4 t = *(const float4*)(T + (size_t)(r & (S_ - 1)) * D_ + c);
    float4* cp = (float4*)(C + (size_t)r * D_ + c);
    float4 v = *cp;
    v.x += sign * t.x; v.y += sign * t.y; v.z += sign * t.z; v.w += sign * t.w;
    *cp = v;
  }
}

// ---------------- fp32 -> bf16 elementwise convert ----------------
__global__ __launch_bounds__(256) void cvt_kernel(const float* __restrict__ src,
                                                  unsigned short* __restrict__ dst,
                                                  int n4) {
  for (int i = blockIdx.x * blockDim.x + threadIdx.x; i < n4;
       i += gridDim.x * blockDim.x) {
    float4 v = *(const float4*)(src + (size_t)i * 4);
    ushort4 o;
    o.x = f2b(v.x); o.y = f2b(v.y); o.z = f2b(v.z); o.w = f2b(v.w);
    *(ushort4*)(dst + (size_t)i * 4) = o;
  }
}

// ---------------- V transpose: fp32 [b,s,h,dk] -> bf16 [b,h,dk,s] ----------------
__global__ __launch_bounds__(256) void vt_kernel(const float* __restrict__ vv,
                                                 unsigned short* __restrict__ vt) {
  __shared__ __align__(16) float tile[64][68];
  const int bh = blockIdx.x;
  const int b = bh >> 3, h = bh & 7;
  const int s0 = blockIdx.y * 64;
  const int t = threadIdx.x;
  #pragma unroll
  for (int i = 0; i < 4; ++i) {
    int lin = t + i * 256;                 // 0..1023 float4s
    int row = lin >> 4;
    int c4 = (lin & 15) * 4;
    float4 v = *(const float4*)(vv + (size_t)(b * S_ + s0 + row) * D_ + h * DK_ + c4);
    *(float4*)&tile[row][c4] = v;
  }
  __syncthreads();
  #pragma unroll
  for (int i = 0; i < 4; ++i) {
    int lin = t + i * 256;
    int d = lin >> 4;
    int s4 = (lin & 15) * 4;
    ushort4 o;
    o.x = f2b(tile[s4 + 0][d]);
    o.y = f2b(tile[s4 + 1][d]);
    o.z = f2b(tile[s4 + 2][d]);
    o.w = f2b(tile[s4 + 3][d]);
    *(ushort4*)(vt + ((size_t)bh * DK_ + d) * S_ + s0 + s4) = o;
  }
}

// ---------------- MFMA complex-hybrid flash attention ----------------
// grid (S/64, B*H), block 256 = 4 waves; wave w owns q rows [blk*64+w*16, +16).
// K-chunk = 32 keys staged in LDS per iteration.
__global__ __launch_bounds__(256) void attn_mfma(const unsigned short* __restrict__ QR,
                                                 const unsigned short* __restrict__ QI,
                                                 const unsigned short* __restrict__ KR,
                                                 const unsigned short* __restrict__ KI,
                                                 const unsigned short* __restrict__ VT,
                                                 float* __restrict__ CTX) {
  __shared__ __align__(16) short kr_s[32][72];    // [key][d], pad 8
  __shared__ __align__(16) short ki_s[32][72];
  __shared__ __align__(16) short vt_s[64][40];    // [d][key], pad 8
  __shared__ __align__(16) short p_s[4][16][40];  // per-wave P round-trip

  const int bh = blockIdx.y;
  const int b = bh >> 3, h = bh & 7;
  const int tid = threadIdx.x;
  const int w = tid >> 6;
  const int lane = tid & 63;
  const int col = lane & 15;       // C-layout col / A,B row selector
  const int quad = lane >> 4;      // 0..3
  const int q0w = blockIdx.x * 64 + w * 16;
  const size_t rowQ = (size_t)(b * S_ + q0w + col) * D_ + h * DK_;

  // Q fragments (A-layout): lane holds Q[q0w+col][d = quad*8 + j (+32)]
  bfrag qr0 = *(const bfrag*)(QR + rowQ + quad * 8);
  bfrag qr1 = *(const bfrag*)(QR + rowQ + 32 + quad * 8);
  bfrag qi0 = *(const bfrag*)(QI + rowQ + quad * 8);
  bfrag qi1 = *(const bfrag*)(QI + rowQ + 32 + quad * 8);

  facc o0 = {0,0,0,0}, o1 = {0,0,0,0}, o2 = {0,0,0,0}, o3 = {0,0,0,0};
  float m_s[4] = {-1e30f, -1e30f, -1e30f, -1e30f};
  float l_s[4] = {0.f, 0.f, 0.f, 0.f};

  // staging indices
  const int krow = tid >> 3, kseg = tid & 7;    // K: 32 rows x 8 segs
  const int vrow = tid >> 2, vseg = tid & 3;    // Vt: 64 rows x 4 segs
  const size_t kbase = (size_t)(b * S_) * D_ + h * DK_;
  const size_t vtbase = (size_t)bh * DK_ * S_;

  for (int c0 = 0; c0 < S_; c0 += 32) {
    __syncthreads();   // protect previous chunk's LDS reads
    {
      const unsigned short* gkr = KR + kbase + (size_t)(c0 + krow) * D_ + kseg * 8;
      const unsigned short* gki = KI + kbase + (size_t)(c0 + krow) * D_ + kseg * 8;
      *(int4*)&kr_s[krow][kseg * 8] = *(const int4*)gkr;
      *(int4*)&ki_s[krow][kseg * 8] = *(const int4*)gki;
      const unsigned short* gvt = VT + vtbase + (size_t)vrow * S_ + c0 + vseg * 8;
      *(int4*)&vt_s[vrow][vseg * 8] = *(const int4*)gvt;
    }
    __syncthreads();

    // ---- scores: two 16x16 k-tiles ----
    facc sr0 = {0,0,0,0}, si0 = {0,0,0,0}, sr1 = {0,0,0,0}, si1 = {0,0,0,0};
    #pragma unroll
    for (int t = 0; t < 2; ++t) {
      bfrag kr_h0 = *(const bfrag*)&kr_s[t * 16 + col][quad * 8];
      bfrag kr_h1 = *(const bfrag*)&kr_s[t * 16 + col][32 + quad * 8];
      bfrag ki_h0 = *(const bfrag*)&ki_s[t * 16 + col][quad * 8];
      bfrag ki_h1 = *(const bfrag*)&ki_s[t * 16 + col][32 + quad * 8];
      bfrag nki_h0, nki_h1;
      #pragma unroll
      for (int j = 0; j < 8; ++j) {
        nki_h0[j] = ki_h0[j] ^ (short)0x8000;
        nki_h1[j] = ki_h1[j] ^ (short)0x8000;
      }
      facc sr = {0,0,0,0}, si = {0,0,0,0};
      sr = __builtin_amdgcn_mfma_f32_16x16x32_bf16(qr0, kr_h0, sr, 0, 0, 0);
      sr = __builtin_amdgcn_mfma_f32_16x16x32_bf16(qr1, kr_h1, sr, 0, 0, 0);
      sr = __builtin_amdgcn_mfma_f32_16x16x32_bf16(qi0, ki_h0, sr, 0, 0, 0);
      sr = __builtin_amdgcn_mfma_f32_16x16x32_bf16(qi1, ki_h1, sr, 0, 0, 0);
      si = __builtin_amdgcn_mfma_f32_16x16x32_bf16(qi0, kr_h0, si, 0, 0, 0);
      si = __builtin_amdgcn_mfma_f32_16x16x32_bf16(qi1, kr_h1, si, 0, 0, 0);
      si = __builtin_amdgcn_mfma_f32_16x16x32_bf16(qr0, nki_h0, si, 0, 0, 0);
      si = __builtin_amdgcn_mfma_f32_16x16x32_bf16(qr1, nki_h1, si, 0, 0, 0);
      if (t == 0) { sr0 = sr; si0 = si; } else { sr1 = sr; si1 = si; }
    }

    // ---- hybrid score + online softmax (per lane: 4 rows x 2 cols) ----
    float sc0[4], sc1[4];
    #pragma unroll
    for (int r = 0; r < 4; ++r) {
      float a = sr0[r] * 0.125f, bb = si0[r] * 0.125f;
      float mag = sqrtf(a * a + bb * bb);
      float ph = (mag == 0.f) ? 1.f : a / mag;
      sc0[r] = (mag + 0.3f * ph) * 0.125f;
      a = sr1[r] * 0.125f; bb = si1[r] * 0.125f;
      mag = sqrtf(a * a + bb * bb);
      ph = (mag == 0.f) ? 1.f : a / mag;
      sc1[r] = (mag + 0.3f * ph) * 0.125f;
    }
    float alpha[4];
    #pragma unroll
    for (int r = 0; r < 4; ++r) {
      float rm = fmaxf(sc0[r], sc1[r]);
      rm = fmaxf(rm, __shfl_xor(rm, 1));
      rm = fmaxf(rm, __shfl_xor(rm, 2));
      rm = fmaxf(rm, __shfl_xor(rm, 4));
      rm = fmaxf(rm, __shfl_xor(rm, 8));
      float newm = fmaxf(m_s[r], rm);
      alpha[r] = __expf(m_s[r] - newm);
      float p0 = __expf(sc0[r] - newm);
      float p1 = __expf(sc1[r] - newm);
      m_s[r] = newm;
      float rs = p0 + p1;
      rs += __shfl_xor(rs, 1);
      rs += __shfl_xor(rs, 2);
      rs += __shfl_xor(rs, 4);
      rs += __shfl_xor(rs, 8);
      l_s[r] = l_s[r] * alpha[r] + rs;
      p_s[w][quad * 4 + r][col]      = (short)f2b(p0);
      p_s[w][quad * 4 + r][16 + col] = (short)f2b(p1);
    }
    #pragma unroll
    for (int r = 0; r < 4; ++r) {
      o0[r] *= alpha[r]; o1[r] *= alpha[r];
      o2[r] *= alpha[r]; o3[r] *= alpha[r];
    }
    __syncthreads();   // P LDS write -> read (wave-private, but keep ordered)

    // ---- PV: P (A-layout) x V-chunk -> 4 d-tiles ----
    bfrag pf = *(const bfrag*)&p_s[w][col][quad * 8];
    bfrag vf0 = *(const bfrag*)&vt_s[0 * 16 + col][quad * 8];
    bfrag vf1 = *(const bfrag*)&vt_s[1 * 16 + col][quad * 8];
    bfrag vf2 = *(const bfrag*)&vt_s[2 * 16 + col][quad * 8];
    bfrag vf3 = *(const bfrag*)&vt_s[3 * 16 + col][quad * 8];
    o0 = __builtin_amdgcn_mfma_f32_16x16x32_bf16(pf, vf0, o0, 0, 0, 0);
    o1 = __builtin_amdgcn_mfma_f32_16x16x32_bf16(pf, vf1, o1, 0, 0, 0);
    o2 = __builtin_amdgcn_mfma_f32_16x16x32_bf16(pf, vf2, o2, 0, 0, 0);
    o3 = __builtin_amdgcn_mfma_f32_16x16x32_bf16(pf, vf3, o3, 0, 0, 0);
  }

  // ---- epilogue: divide by l, write ctx [b,s,h*64+d] ----
  #pragma unroll
  for (int r = 0; r < 4; ++r) {
    float inv = 1.f / l_s[r];
    size_t orow = (size_t)(b * S_ + q0w + quad * 4 + r) * D_ + h * DK_;
    CTX[orow + 0  + col] = o0[r] * inv;
    CTX[orow + 16 + col] = o1[r] * inv;
    CTX[orow + 32 + col] = o2[r] * inv;
    CTX[orow + 48 + col] = o3[r] * inv;
  }
}

// ---------------- layernorm ----------------
__global__ __launch_bounds__(256) void ln_kernel(const float* __restrict__ X,
                                                 const float* __restrict__ R,
                                                 const float* __restrict__ g,
                                                 const float* __restrict__ be,
                                                 float* __restrict__ Out) {
  const int lane = threadIdx.x & 63;
  const int wv = threadIdx.x >> 6;
  const int row = blockIdx.x * 4 + wv;
  const float* xp = X + (size_t)row * D_;
  const float* rp = R + (size_t)row * D_;
  float x[8];
  float s = 0.f;
  #pragma unroll
  for (int i = 0; i < 8; ++i) {
    int d = i * 64 + lane;
    x[i] = xp[d] + rp[d];
    s += x[i];
  }
  s += __shfl_xor(s, 32); s += __shfl_xor(s, 16); s += __shfl_xor(s, 8);
  s += __shfl_xor(s, 4);  s += __shfl_xor(s, 2);  s += __shfl_xor(s, 1);
  float mu = s * (1.f / 512.f);
  float vs = 0.f;
  #pragma unroll
  for (int i = 0; i < 8; ++i) { float d = x[i] - mu; vs += d * d; }
  vs += __shfl_xor(vs, 32); vs += __shfl_xor(vs, 16); vs += __shfl_xor(vs, 8);
  vs += __shfl_xor(vs, 4);  vs += __shfl_xor(vs, 2);  vs += __shfl_xor(vs, 1);
  float rstd = rsqrtf(vs * (1.f / 512.f) + 1e-5f);
  float* op = Out + (size_t)row * D_;
  #pragma unroll
  for (int i = 0; i < 8; ++i) {
    int d = i * 64 + lane;
    op[d] = (x[i] - mu) * rstd * g[d] + be[d];
  }
}

// ---------------- classifier head ----------------
__global__ __launch_bounds__(256) void head_kernel(const float* __restrict__ Z,
                                                   const float* __restrict__ hw,
                                                   const float* __restrict__ hb,
                                                   float* __restrict__ out) {
  const int lane = threadIdx.x & 63;
  const int wv = threadIdx.x >> 6;
  const int row = blockIdx.x * 4 + wv;
  const float* zp = Z + (size_t)row * D_;
  float a0 = 0.f, a1 = 0.f;
  #pragma unroll
  for (int i = 0; i < 8; ++i) {
    int d = i * 64 + lane;
    float z = zp[d];
    a0 += z * hw[d * 2];
    a1 += z * hw[d * 2 + 1];
  }
  a0 += __shfl_xor(a0, 32); a0 += __shfl_xor(a0, 16); a0 += __shfl_xor(a0, 8);
  a0 += __shfl_xor(a0, 4);  a0 += __shfl_xor(a0, 2);  a0 += __shfl_xor(a0, 1);
  a1 += __shfl_xor(a1, 32); a1 += __shfl_xor(a1, 16); a1 += __shfl_xor(a1, 8);
  a1 += __shfl_xor(a1, 4);  a1 += __shfl_xor(a1, 2);  a1 += __shfl_xor(a1, 1);
  if (lane == 0) {
    out[row * 2]     = a0 + hb[0];
    out[row * 2 + 1] = a1 + hb[1];
  }
}

extern "C" void kernel_launch(void* const* d_in, const int* in_sizes, int n_in,
                              void* d_out, int out_size, void* d_ws, size_t ws_size,
                              hipStream_t stream) {
  const int*   tokens = (const int*)  d_in[0];
  const float* embed  = (const float*)d_in[1];
  const float* Wqr = (const float*)d_in[2];
  const float* Wqi = (const float*)d_in[3];
  const float* Wkr = (const float*)d_in[4];
  const float* Wki = (const float*)d_in[5];
  const float* Wv  = (const float*)d_in[6];
  const float* Wo  = (const float*)d_in[7];
  const float* bo  = (const float*)d_in[8];
  const float* W1  = (const float*)d_in[9];
  const float* b1  = (const float*)d_in[10];
  const float* W2  = (const float*)d_in[11];
  const float* b2  = (const float*)d_in[12];
  const float* g1  = (const float*)d_in[13];
  const float* be1 = (const float*)d_in[14];
  const float* g2  = (const float*)d_in[15];
  const float* be2 = (const float*)d_in[16];
  const float* hw  = (const float*)d_in[17];
  const float* hb  = (const float*)d_in[18];
  float* out = (float*)d_out;

  float* ws = (float*)d_ws;
  const size_t NBD = (size_t)BS_ * D_;       // 2M floats
  float* zr   = ws;  ws += NBD;
  float* zi   = ws;  ws += (size_t)S_ * D_;
  float* qr   = ws;  ws += NBD;              // ff aliases qr..ki
  float* qi   = ws;  ws += NBD;
  float* kr   = ws;  ws += NBD;
  float* ki   = ws;  ws += NBD;
  float* vv   = ws;  ws += NBD;
  float* ctx  = ws;  ws += NBD;
  float* hbuf = ws;  ws += NBD;
  float* z1   = ws;  ws += NBD;
  float* tmp  = ws;  ws += (size_t)S_ * D_;
  float* ff   = qr;                          // [BS_, DFF_]

  // bf16 buffers alias fp32 regions that are dead during attention:
  //   hbuf (Wo output, written after attn)  <- qr_b, qi_b
  //   z1   (ln1 output, written after attn) <- kr_b, ki_b
  //   tmp  (layer-0 zi projections, dead)   <- vt_b
  unsigned short* qr_b = (unsigned short*)hbuf;
  unsigned short* qi_b = qr_b + NBD;
  unsigned short* kr_b = (unsigned short*)z1;
  unsigned short* ki_b = kr_b + NBD;
  unsigned short* vt_b = (unsigned short*)tmp;

  embed_kernel<<<BS_, 128, 0, stream>>>(tokens, embed, zr);
  zi_kernel<<<S_, 128, 0, stream>>>(zi);

  for (int l = 0; l < L_; ++l) {
    const float* wqr = Wqr + (size_t)l * D_ * D_;
    const float* wqi = Wqi + (size_t)l * D_ * D_;
    const float* wkr = Wkr + (size_t)l * D_ * D_;
    const float* wki = Wki + (size_t)l * D_ * D_;
    const float* wv  = Wv  + (size_t)l * D_ * D_;
    const float* wo  = Wo  + (size_t)l * D_ * D_;
    const float* w1  = W1  + (size_t)l * D_ * DFF_;
    const float* w2  = W2  + (size_t)l * DFF_ * D_;

    dim3 g512(D_ / 64, BS_ / 64);
    gemm64<<<g512, 256, 0, stream>>>(zr, wqr, nullptr, qr, BS_, D_, D_, 0);
    gemm64<<<g512, 256, 0, stream>>>(zr, wqi, nullptr, qi, BS_, D_, D_, 0);
    gemm64<<<g512, 256, 0, stream>>>(zr, wkr, nullptr, kr, BS_, D_, D_, 0);
    gemm64<<<g512, 256, 0, stream>>>(zr, wki, nullptr, ki, BS_, D_, D_, 0);
    gemm64<<<g512, 256, 0, stream>>>(zr, wv,  nullptr, vv, BS_, D_, D_, 0);

    if (l == 0) {
      dim3 gHalf(D_ / 64, S_ / 64);
      gemm64<<<gHalf, 256, 0, stream>>>(zi, wqi, nullptr, tmp, S_, D_, D_, 0);
      combine_kernel<<<512, 256, 0, stream>>>(qr, tmp, -1.f);
      gemm64<<<gHalf, 256, 0, stream>>>(zi, wqr, nullptr, tmp, S_, D_, D_, 0);
      combine_kernel<<<512, 256, 0, stream>>>(qi, tmp, +1.f);
      gemm64<<<gHalf, 256, 0, stream>>>(zi, wki, nullptr, tmp, S_, D_, D_, 0);
      combine_kernel<<<512, 256, 0, stream>>>(kr, tmp, -1.f);
      gemm64<<<gHalf, 256, 0, stream>>>(zi, wkr, nullptr, tmp, S_, D_, D_, 0);
      combine_kernel<<<512, 256, 0, stream>>>(ki, tmp, +1.f);
    }

    // convert to bf16 for MFMA attention
    const int n4 = BS_ * D_ / 4;
    cvt_kernel<<<1024, 256, 0, stream>>>(qr, qr_b, n4);
    cvt_kernel<<<1024, 256, 0, stream>>>(qi, qi_b, n4);
    cvt_kernel<<<1024, 256, 0, stream>>>(kr, kr_b, n4);
    cvt_kernel<<<1024, 256, 0, stream>>>(ki, ki_b, n4);
    vt_kernel<<<dim3(B_ * H_, S_ / 64), 256, 0, stream>>>(vv, vt_b);

    dim3 ga(S_ / 64, B_ * H_);               // (32, 16)
    attn_mfma<<<ga, 256, 0, stream>>>(qr_b, qi_b, kr_b, ki_b, vt_b, ctx);

    gemm64<<<g512, 256, 0, stream>>>(ctx, wo, bo + l * D_, hbuf, BS_, D_, D_, 0);
    ln_kernel<<<BS_ / 4, 256, 0, stream>>>(zr, hbuf, g1 + l * D_, be1 + l * D_, z1);

    dim3 gff1(DFF_ / 64, BS_ / 64);
    gemm64<<<gff1, 256, 0, stream>>>(z1, w1, b1 + l * DFF_, ff, BS_, DFF_, D_, 1);
    gemm64<<<g512, 256, 0, stream>>>(ff, w2, b2 + l * D_, hbuf, BS_, D_, DFF_, 0);
    ln_kernel<<<BS_ / 4, 256, 0, stream>>>(z1, hbuf, g2 + l * D_, be2 + l * D_, zr);
  }

  head_kernel<<<BS_ / 4, 256, 0, stream>>>(zr, hw, hb, out);
}

// Round 3
// 780.171 us; speedup vs baseline: 12.9980x; 2.0834x over previous
//
#include <hip/hip_runtime.h>

#define B_   2
#define S_   2048
#define D_   512
#define H_   8
#define DK_  64
#define DFF_ 2048
#define L_   2
#define BS_  (B_*S_)   // 4096
#define NPROJ 2560     // qr|qi|kr|ki|v concatenated

typedef __attribute__((ext_vector_type(8))) short bfrag;   // 8 bf16 in 4 VGPRs
typedef __attribute__((ext_vector_type(4))) float facc;    // 4 fp32 acc

__device__ __forceinline__ unsigned short f2b(float f) {
  union { float f; unsigned int u; } c; c.f = f;
  unsigned int u = c.u;
  u += 0x7fffu + ((u >> 16) & 1);    // RNE
  return (unsigned short)(u >> 16);
}

__device__ __forceinline__ void async_copy16(const void* g, void* l) {
  __builtin_amdgcn_global_load_lds((const __attribute__((address_space(1))) void*)g,
                                   (__attribute__((address_space(3))) void*)l,
                                   16, 0, 0);
}

// ---------------- embedding gather: zr fp32 + acat bf16 left half ----------------
__global__ __launch_bounds__(128) void embed_kernel(const int* __restrict__ tokens,
                                                    const float* __restrict__ embed,
                                                    float* __restrict__ zr,
                                                    unsigned short* __restrict__ acat) {
  int row = blockIdx.x;
  int tok = tokens[row];
  float4 v = ((const float4*)(embed + (size_t)tok * D_))[threadIdx.x];
  ((float4*)(zr + (size_t)row * D_))[threadIdx.x] = v;
  ushort4 o; o.x = f2b(v.x); o.y = f2b(v.y); o.z = f2b(v.z); o.w = f2b(v.w);
  *(ushort4*)(acat + (size_t)row * 1024 + threadIdx.x * 4) = o;
}

// ---------------- zi bf16 into acat right half (broadcast over batch) ----------------
__global__ __launch_bounds__(128) void zi_kernel(unsigned short* __restrict__ acat) {
  int row = blockIdx.x;                 // 0..4095
  int s = row & (S_ - 1);
  int d0 = threadIdx.x * 4;
  const double LN1E4 = 9.210340371976184;
  #pragma unroll
  for (int t = 0; t < 4; ++t) {
    int d = d0 + t;
    int jj = d >> 1;
    double freq = exp(-((double)jj / 256.0) * LN1E4);
    float val = (float)sin((double)s * freq);
    acat[(size_t)row * 1024 + 512 + d] = f2b(val);
  }
}

// ---------------- weight concat+transpose for fused projection ----------------
// dst [NPROJ, KA] bf16; KA=1024 (layer0, zi folded) or 512 (layer1)
__global__ __launch_bounds__(256) void wcat_kernel(const float* __restrict__ wqr,
                                                   const float* __restrict__ wqi,
                                                   const float* __restrict__ wkr,
                                                   const float* __restrict__ wki,
                                                   const float* __restrict__ wv,
                                                   unsigned short* __restrict__ dst,
                                                   int KA) {
  __shared__ float tile[64][68];
  const int tid = threadIdx.x;
  const int n0 = blockIdx.x * 64, k0 = blockIdx.y * 64;
  const int p = n0 >> 9, nn0 = n0 & 511;
  const float* src;
  float sign = 1.f;
  bool zero = false;
  if (k0 < 512) {
    const float* tops[5] = {wqr, wqi, wkr, wki, wv};
    src = tops[p];
  } else {
    const float* bots[5] = {wqi, wqr, wki, wkr, nullptr};
    const float sg[5] = {-1.f, 1.f, -1.f, 1.f, 0.f};
    src = bots[p]; sign = sg[p]; zero = (p == 4);
  }
  const int kk0 = k0 & 511;
  #pragma unroll
  for (int i = 0; i < 4; ++i) {
    int lin = tid + i * 256;
    int row = lin >> 4, c4 = (lin & 15) * 4;
    float4 v = make_float4(0.f, 0.f, 0.f, 0.f);
    if (!zero) v = *(const float4*)(src + (size_t)(kk0 + row) * 512 + nn0 + c4);
    *(float4*)&tile[row][c4] = v;
  }
  __syncthreads();
  #pragma unroll
  for (int i = 0; i < 4; ++i) {
    int lin = tid + i * 256;
    int n = lin >> 4, kc4 = (lin & 15) * 4;
    ushort4 o;
    o.x = f2b(sign * tile[kc4 + 0][n]);
    o.y = f2b(sign * tile[kc4 + 1][n]);
    o.z = f2b(sign * tile[kc4 + 2][n]);
    o.w = f2b(sign * tile[kc4 + 3][n]);
    *(ushort4*)(dst + (size_t)(n0 + n) * KA + k0 + kc4) = o;
  }
}

// ---------------- generic weight transpose: fp32 [K,N] -> bf16 [N,K] ----------------
__global__ __launch_bounds__(256) void wtr_kernel(const float* __restrict__ W,
                                                  unsigned short* __restrict__ dst,
                                                  int K, int N) {
  __shared__ float tile[64][68];
  const int tid = threadIdx.x;
  const int n0 = blockIdx.x * 64, k0 = blockIdx.y * 64;
  #pragma unroll
  for (int i = 0; i < 4; ++i) {
    int lin = tid + i * 256;
    int row = lin >> 4, c4 = (lin & 15) * 4;
    *(float4*)&tile[row][c4] = *(const float4*)(W + (size_t)(k0 + row) * N + n0 + c4);
  }
  __syncthreads();
  #pragma unroll
  for (int i = 0; i < 4; ++i) {
    int lin = tid + i * 256;
    int n = lin >> 4, kc4 = (lin & 15) * 4;
    ushort4 o;
    o.x = f2b(tile[kc4 + 0][n]);
    o.y = f2b(tile[kc4 + 1][n]);
    o.z = f2b(tile[kc4 + 2][n]);
    o.w = f2b(tile[kc4 + 3][n]);
    *(ushort4*)(dst + (size_t)(n0 + n) * K + k0 + kc4) = o;
  }
}

// ---------------- bf16 MFMA GEMM (m97 pattern): C = A[M,K(lda)] @ Bt[N,K]^T ----------------
// TM x 128 tile, 256 threads (4 waves), BK=32, global_load_lds width 16.
template<int TM>
__global__ __launch_bounds__(256) void gemm_bf16(const unsigned short* __restrict__ A,
                                                 const unsigned short* __restrict__ Bt,
                                                 const float* __restrict__ bias,
                                                 float* __restrict__ outF,
                                                 unsigned short* __restrict__ outB,
                                                 int M, int N, int K, int lda, int relu) {
  constexpr int MT = TM / 32;          // m-tiles per wave (4 for TM=128, 2 for TM=64)
  __shared__ short smem[(TM + 128) * 32];
  short* A_s = smem;                   // [TM][32]
  short* B_s = smem + TM * 32;         // [128][32]

  const int tid = threadIdx.x;
  const int w = tid >> 6, lane = tid & 63;
  const int col = lane & 15, quad = lane >> 4;
  const int m0 = blockIdx.y * TM, n0 = blockIdx.x * 128;
  const int wrow = (w >> 1) * (TM / 2);
  const int wcol = (w & 1) * 64;

  const int srow = lane >> 2;          // 0..15
  const int skk  = (lane & 3) * 8;     // k element offset

  facc acc[MT][4];
  #pragma unroll
  for (int i = 0; i < MT; ++i)
    #pragma unroll
    for (int j = 0; j < 4; ++j) acc[i][j] = (facc){0.f, 0.f, 0.f, 0.f};

  for (int k0 = 0; k0 < K; k0 += 32) {
    __syncthreads();
    #pragma unroll
    for (int rd = 0; rd < TM / 64; ++rd) {
      int row = rd * 64 + w * 16 + srow;
      async_copy16(A + (size_t)(m0 + row) * lda + k0 + skk, &A_s[row * 32 + skk]);
    }
    #pragma unroll
    for (int rd = 0; rd < 2; ++rd) {
      int row = rd * 64 + w * 16 + srow;
      async_copy16(Bt + (size_t)(n0 + row) * K + k0 + skk, &B_s[row * 32 + skk]);
    }
    __syncthreads();

    bfrag af[MT], bf[4];
    #pragma unroll
    for (int i = 0; i < MT; ++i)
      af[i] = *(const bfrag*)&A_s[(wrow + i * 16 + col) * 32 + quad * 8];
    #pragma unroll
    for (int j = 0; j < 4; ++j)
      bf[j] = *(const bfrag*)&B_s[(wcol + j * 16 + col) * 32 + quad * 8];
    #pragma unroll
    for (int i = 0; i < MT; ++i)
      #pragma unroll
      for (int j = 0; j < 4; ++j)
        acc[i][j] = __builtin_amdgcn_mfma_f32_16x16x32_bf16(af[i], bf[j], acc[i][j], 0, 0, 0);
  }

  #pragma unroll
  for (int i = 0; i < MT; ++i) {
    #pragma unroll
    for (int j = 0; j < 4; ++j) {
      int colIdx = n0 + wcol + j * 16 + col;
      float b = bias ? bias[colIdx] : 0.f;
      #pragma unroll
      for (int r = 0; r < 4; ++r) {
        int rowIdx = m0 + wrow + i * 16 + quad * 4 + r;
        float v = acc[i][j][r] + b;
        if (relu) v = fmaxf(v, 0.f);
        if (outF) outF[(size_t)rowIdx * N + colIdx] = v;
        if (outB) outB[(size_t)rowIdx * N + colIdx] = f2b(v);
      }
    }
  }
}

// ---------------- V transpose: Q4 cols [2048,2560) -> bf16 [b,h,dk,s] ----------------
__global__ __launch_bounds__(256) void vt_kernel(const unsigned short* __restrict__ Q4,
                                                 unsigned short* __restrict__ vt) {
  __shared__ short tile[64][80];
  const int bh = blockIdx.x;
  const int b = bh >> 3, h = bh & 7;
  const int s0 = blockIdx.y * 64;
  const int tid = threadIdx.x;
  #pragma unroll
  for (int i = 0; i < 2; ++i) {
    int lin = tid + i * 256;                  // 0..511
    int row = lin >> 3;                       // 0..63
    int c8 = (lin & 7) * 8;
    *(int4*)&tile[row][c8] =
      *(const int4*)(Q4 + (size_t)(b * S_ + s0 + row) * NPROJ + 2048 + h * DK_ + c8);
  }
  __syncthreads();
  #pragma unroll
  for (int i = 0; i < 2; ++i) {
    int lin = tid + i * 256;
    int d = lin >> 3;
    int s8 = (lin & 7) * 8;
    short tmp[8];
    #pragma unroll
    for (int t = 0; t < 8; ++t) tmp[t] = tile[s8 + t][d];
    *(int4*)(vt + ((size_t)bh * DK_ + d) * S_ + s0 + s8) = *(const int4*)tmp;
  }
}

// ---------------- MFMA complex-hybrid flash attention (reads fused Q4) ----------------
__global__ __launch_bounds__(256) void attn_mfma(const unsigned short* __restrict__ Q4,
                                                 const unsigned short* __restrict__ VT,
                                                 unsigned short* __restrict__ CTXB) {
  __shared__ __align__(16) short kr_s[32][72];
  __shared__ __align__(16) short ki_s[32][72];
  __shared__ __align__(16) short vt_s[64][40];
  __shared__ __align__(16) short p_s[4][16][40];

  const int bh = blockIdx.y;
  const int b = bh >> 3, h = bh & 7;
  const int tid = threadIdx.x;
  const int w = tid >> 6;
  const int lane = tid & 63;
  const int col = lane & 15;
  const int quad = lane >> 4;
  const int q0w = blockIdx.x * 64 + w * 16;
  const size_t rowQ = (size_t)(b * S_ + q0w + col) * NPROJ;
  const int hoff = h * DK_;

  bfrag qr0 = *(const bfrag*)(Q4 + rowQ + hoff + quad * 8);
  bfrag qr1 = *(const bfrag*)(Q4 + rowQ + hoff + 32 + quad * 8);
  bfrag qi0 = *(const bfrag*)(Q4 + rowQ + 512 + hoff + quad * 8);
  bfrag qi1 = *(const bfrag*)(Q4 + rowQ + 512 + hoff + 32 + quad * 8);

  facc o0 = {0,0,0,0}, o1 = {0,0,0,0}, o2 = {0,0,0,0}, o3 = {0,0,0,0};
  float m_s[4] = {-1e30f, -1e30f, -1e30f, -1e30f};
  float l_s[4] = {0.f, 0.f, 0.f, 0.f};

  const int krow = tid >> 3, kseg = tid & 7;
  const int vrow = tid >> 2, vseg = tid & 3;
  const size_t vtbase = (size_t)bh * DK_ * S_;

  for (int c0 = 0; c0 < S_; c0 += 32) {
    __syncthreads();
    {
      const size_t krbase = (size_t)(b * S_ + c0 + krow) * NPROJ;
      *(int4*)&kr_s[krow][kseg * 8] = *(const int4*)(Q4 + krbase + 1024 + hoff + kseg * 8);
      *(int4*)&ki_s[krow][kseg * 8] = *(const int4*)(Q4 + krbase + 1536 + hoff + kseg * 8);
      *(int4*)&vt_s[vrow][vseg * 8] = *(const int4*)(VT + vtbase + (size_t)vrow * S_ + c0 + vseg * 8);
    }
    __syncthreads();

    facc sr0 = {0,0,0,0}, si0 = {0,0,0,0}, sr1 = {0,0,0,0}, si1 = {0,0,0,0};
    #pragma unroll
    for (int t = 0; t < 2; ++t) {
      bfrag kr_h0 = *(const bfrag*)&kr_s[t * 16 + col][quad * 8];
      bfrag kr_h1 = *(const bfrag*)&kr_s[t * 16 + col][32 + quad * 8];
      bfrag ki_h0 = *(const bfrag*)&ki_s[t * 16 + col][quad * 8];
      bfrag ki_h1 = *(const bfrag*)&ki_s[t * 16 + col][32 + quad * 8];
      bfrag nki_h0, nki_h1;
      #pragma unroll
      for (int j = 0; j < 8; ++j) {
        nki_h0[j] = ki_h0[j] ^ (short)0x8000;
        nki_h1[j] = ki_h1[j] ^ (short)0x8000;
      }
      facc sr = {0,0,0,0}, si = {0,0,0,0};
      sr = __builtin_amdgcn_mfma_f32_16x16x32_bf16(qr0, kr_h0, sr, 0, 0, 0);
      sr = __builtin_amdgcn_mfma_f32_16x16x32_bf16(qr1, kr_h1, sr, 0, 0, 0);
      sr = __builtin_amdgcn_mfma_f32_16x16x32_bf16(qi0, ki_h0, sr, 0, 0, 0);
      sr = __builtin_amdgcn_mfma_f32_16x16x32_bf16(qi1, ki_h1, sr, 0, 0, 0);
      si = __builtin_amdgcn_mfma_f32_16x16x32_bf16(qi0, kr_h0, si, 0, 0, 0);
      si = __builtin_amdgcn_mfma_f32_16x16x32_bf16(qi1, kr_h1, si, 0, 0, 0);
      si = __builtin_amdgcn_mfma_f32_16x16x32_bf16(qr0, nki_h0, si, 0, 0, 0);
      si = __builtin_amdgcn_mfma_f32_16x16x32_bf16(qr1, nki_h1, si, 0, 0, 0);
      if (t == 0) { sr0 = sr; si0 = si; } else { sr1 = sr; si1 = si; }
    }

    float sc0[4], sc1[4];
    #pragma unroll
    for (int r = 0; r < 4; ++r) {
      float a = sr0[r] * 0.125f, bb = si0[r] * 0.125f;
      float mag = sqrtf(a * a + bb * bb);
      float ph = (mag == 0.f) ? 1.f : a / mag;
      sc0[r] = (mag + 0.3f * ph) * 0.125f;
      a = sr1[r] * 0.125f; bb = si1[r] * 0.125f;
      mag = sqrtf(a * a + bb * bb);
      ph = (mag == 0.f) ? 1.f : a / mag;
      sc1[r] = (mag + 0.3f * ph) * 0.125f;
    }
    float alpha[4];
    #pragma unroll
    for (int r = 0; r < 4; ++r) {
      float rm = fmaxf(sc0[r], sc1[r]);
      rm = fmaxf(rm, __shfl_xor(rm, 1));
      rm = fmaxf(rm, __shfl_xor(rm, 2));
      rm = fmaxf(rm, __shfl_xor(rm, 4));
      rm = fmaxf(rm, __shfl_xor(rm, 8));
      float newm = fmaxf(m_s[r], rm);
      alpha[r] = __expf(m_s[r] - newm);
      float p0 = __expf(sc0[r] - newm);
      float p1 = __expf(sc1[r] - newm);
      m_s[r] = newm;
      float rs = p0 + p1;
      rs += __shfl_xor(rs, 1);
      rs += __shfl_xor(rs, 2);
      rs += __shfl_xor(rs, 4);
      rs += __shfl_xor(rs, 8);
      l_s[r] = l_s[r] * alpha[r] + rs;
      p_s[w][quad * 4 + r][col]      = (short)f2b(p0);
      p_s[w][quad * 4 + r][16 + col] = (short)f2b(p1);
    }
    #pragma unroll
    for (int r = 0; r < 4; ++r) {
      o0[r] *= alpha[r]; o1[r] *= alpha[r];
      o2[r] *= alpha[r]; o3[r] *= alpha[r];
    }
    __syncthreads();

    bfrag pf = *(const bfrag*)&p_s[w][col][quad * 8];
    bfrag vf0 = *(const bfrag*)&vt_s[0 * 16 + col][quad * 8];
    bfrag vf1 = *(const bfrag*)&vt_s[1 * 16 + col][quad * 8];
    bfrag vf2 = *(const bfrag*)&vt_s[2 * 16 + col][quad * 8];
    bfrag vf3 = *(const bfrag*)&vt_s[3 * 16 + col][quad * 8];
    o0 = __builtin_amdgcn_mfma_f32_16x16x32_bf16(pf, vf0, o0, 0, 0, 0);
    o1 = __builtin_amdgcn_mfma_f32_16x16x32_bf16(pf, vf1, o1, 0, 0, 0);
    o2 = __builtin_amdgcn_mfma_f32_16x16x32_bf16(pf, vf2, o2, 0, 0, 0);
    o3 = __builtin_amdgcn_mfma_f32_16x16x32_bf16(pf, vf3, o3, 0, 0, 0);
  }

  #pragma unroll
  for (int r = 0; r < 4; ++r) {
    float inv = 1.f / l_s[r];
    size_t orow = (size_t)(b * S_ + q0w + quad * 4 + r) * D_ + hoff;
    CTXB[orow + 0  + col] = f2b(o0[r] * inv);
    CTXB[orow + 16 + col] = f2b(o1[r] * inv);
    CTXB[orow + 32 + col] = f2b(o2[r] * inv);
    CTXB[orow + 48 + col] = f2b(o3[r] * inv);
  }
}

// ---------------- layernorm: Out = LN(X + R)*g + be -> fp32 (+bf16) ----------------
__global__ __launch_bounds__(256) void ln_kernel(const float* __restrict__ X,
                                                 const float* __restrict__ R,
                                                 const float* __restrict__ g,
                                                 const float* __restrict__ be,
                                                 float* __restrict__ OutF,
                                                 unsigned short* __restrict__ OutB) {
  const int lane = threadIdx.x & 63;
  const int wv = threadIdx.x >> 6;
  const int row = blockIdx.x * 4 + wv;
  const float* xp = X + (size_t)row * D_;
  const float* rp = R + (size_t)row * D_;
  float x[8];
  float s = 0.f;
  #pragma unroll
  for (int i = 0; i < 8; ++i) {
    int d = i * 64 + lane;
    x[i] = xp[d] + rp[d];
    s += x[i];
  }
  s += __shfl_xor(s, 32); s += __shfl_xor(s, 16); s += __shfl_xor(s, 8);
  s += __shfl_xor(s, 4);  s += __shfl_xor(s, 2);  s += __shfl_xor(s, 1);
  float mu = s * (1.f / 512.f);
  float vs = 0.f;
  #pragma unroll
  for (int i = 0; i < 8; ++i) { float d = x[i] - mu; vs += d * d; }
  vs += __shfl_xor(vs, 32); vs += __shfl_xor(vs, 16); vs += __shfl_xor(vs, 8);
  vs += __shfl_xor(vs, 4);  vs += __shfl_xor(vs, 2);  vs += __shfl_xor(vs, 1);
  float rstd = rsqrtf(vs * (1.f / 512.f) + 1e-5f);
  #pragma unroll
  for (int i = 0; i < 8; ++i) {
    int d = i * 64 + lane;
    float v = (x[i] - mu) * rstd * g[d] + be[d];
    if (OutF) OutF[(size_t)row * D_ + d] = v;
    if (OutB) OutB[(size_t)row * D_ + d] = f2b(v);
  }
}

// ---------------- classifier head ----------------
__global__ __launch_bounds__(256) void head_kernel(const float* __restrict__ Z,
                                                   const float* __restrict__ hw,
                                                   const float* __restrict__ hb,
                                                   float* __restrict__ out) {
  const int lane = threadIdx.x & 63;
  const int wv = threadIdx.x >> 6;
  const int row = blockIdx.x * 4 + wv;
  const float* zp = Z + (size_t)row * D_;
  float a0 = 0.f, a1 = 0.f;
  #pragma unroll
  for (int i = 0; i < 8; ++i) {
    int d = i * 64 + lane;
    float z = zp[d];
    a0 += z * hw[d * 2];
    a1 += z * hw[d * 2 + 1];
  }
  a0 += __shfl_xor(a0, 32); a0 += __shfl_xor(a0, 16); a0 += __shfl_xor(a0, 8);
  a0 += __shfl_xor(a0, 4);  a0 += __shfl_xor(a0, 2);  a0 += __shfl_xor(a0, 1);
  a1 += __shfl_xor(a1, 32); a1 += __shfl_xor(a1, 16); a1 += __shfl_xor(a1, 8);
  a1 += __shfl_xor(a1, 4);  a1 += __shfl_xor(a1, 2);  a1 += __shfl_xor(a1, 1);
  if (lane == 0) {
    out[row * 2]     = a0 + hb[0];
    out[row * 2 + 1] = a1 + hb[1];
  }
}

extern "C" void kernel_launch(void* const* d_in, const int* in_sizes, int n_in,
                              void* d_out, int out_size, void* d_ws, size_t ws_size,
                              hipStream_t stream) {
  const int*   tokens = (const int*)  d_in[0];
  const float* embed  = (const float*)d_in[1];
  const float* Wqr = (const float*)d_in[2];
  const float* Wqi = (const float*)d_in[3];
  const float* Wkr = (const float*)d_in[4];
  const float* Wki = (const float*)d_in[5];
  const float* Wv  = (const float*)d_in[6];
  const float* Wo  = (const float*)d_in[7];
  const float* bo  = (const float*)d_in[8];
  const float* W1  = (const float*)d_in[9];
  const float* b1  = (const float*)d_in[10];
  const float* W2  = (const float*)d_in[11];
  const float* b2  = (const float*)d_in[12];
  const float* g1  = (const float*)d_in[13];
  const float* be1 = (const float*)d_in[14];
  const float* g2  = (const float*)d_in[15];
  const float* be2 = (const float*)d_in[16];
  const float* hw  = (const float*)d_in[17];
  const float* hb  = (const float*)d_in[18];
  float* out = (float*)d_out;

  // workspace carve (bytes); aliases noted
  char* p = (char*)d_ws;
  float* zr = (float*)p;             p += (size_t)BS_ * D_ * 4;          // 8 MB
  unsigned short* acat = (unsigned short*)p;                             // [4096,1024]
  unsigned short* zrb  = acat;       p += (size_t)BS_ * 1024 * 2;        // 8 MB (zrb aliases)
  unsigned short* Q4   = (unsigned short*)p;                             // [4096,2560]
  unsigned short* ffb  = Q4;         p += (size_t)BS_ * NPROJ * 2;       // 20 MB (ffb aliases)
  unsigned short* VT   = (unsigned short*)p; p += (size_t)B_*H_*DK_*S_*2;// 4 MB
  unsigned short* ctxb = (unsigned short*)p; p += (size_t)BS_ * D_ * 2;  // 4 MB
  float* hbuf = (float*)p;           p += (size_t)BS_ * D_ * 4;          // 8 MB
  float* z1   = (float*)p;           p += (size_t)BS_ * D_ * 4;          // 8 MB
  unsigned short* z1b = (unsigned short*)p;  p += (size_t)BS_ * D_ * 2;  // 4 MB
  unsigned short* wsc = (unsigned short*)p;  p += (size_t)NPROJ * 1024 * 2; // 5 MB

  embed_kernel<<<BS_, 128, 0, stream>>>(tokens, embed, zr, acat);
  zi_kernel<<<BS_, 128, 0, stream>>>(acat);

  for (int l = 0; l < L_; ++l) {
    const float* wqr = Wqr + (size_t)l * D_ * D_;
    const float* wqi = Wqi + (size_t)l * D_ * D_;
    const float* wkr = Wkr + (size_t)l * D_ * D_;
    const float* wki = Wki + (size_t)l * D_ * D_;
    const float* wv  = Wv  + (size_t)l * D_ * D_;
    const float* wo  = Wo  + (size_t)l * D_ * D_;
    const float* w1  = W1  + (size_t)l * D_ * DFF_;
    const float* w2  = W2  + (size_t)l * DFF_ * D_;

    const int KA = (l == 0) ? 1024 : 512;
    const unsigned short* Aproj = (l == 0) ? acat : zrb;

    // fused QKV projection
    wcat_kernel<<<dim3(NPROJ / 64, KA / 64), 256, 0, stream>>>(wqr, wqi, wkr, wki, wv, wsc, KA);
    gemm_bf16<128><<<dim3(NPROJ / 128, BS_ / 128), 256, 0, stream>>>(
        Aproj, wsc, nullptr, nullptr, Q4, BS_, NPROJ, KA, KA, 0);

    vt_kernel<<<dim3(B_ * H_, S_ / 64), 256, 0, stream>>>(Q4, VT);
    attn_mfma<<<dim3(S_ / 64, B_ * H_), 256, 0, stream>>>(Q4, VT, ctxb);

    // Wo projection
    wtr_kernel<<<dim3(D_ / 64, D_ / 64), 256, 0, stream>>>(wo, wsc, D_, D_);
    gemm_bf16<64><<<dim3(D_ / 128, BS_ / 64), 256, 0, stream>>>(
        ctxb, wsc, bo + l * D_, hbuf, nullptr, BS_, D_, D_, D_, 0);
    ln_kernel<<<BS_ / 4, 256, 0, stream>>>(zr, hbuf, g1 + l * D_, be1 + l * D_, z1, z1b);

    // FFN
    wtr_kernel<<<dim3(DFF_ / 64, D_ / 64), 256, 0, stream>>>(w1, wsc, D_, DFF_);
    gemm_bf16<128><<<dim3(DFF_ / 128, BS_ / 128), 256, 0, stream>>>(
        z1b, wsc, b1 + l * DFF_, nullptr, ffb, BS_, DFF_, D_, D_, 1);
    wtr_kernel<<<dim3(D_ / 64, DFF_ / 64), 256, 0, stream>>>(w2, wsc, DFF_, D_);
    gemm_bf16<64><<<dim3(D_ / 128, BS_ / 64), 256, 0, stream>>>(
        ffb, wsc, b2 + l * D_, hbuf, nullptr, BS_, D_, DFF_, DFF_, 0);
    ln_kernel<<<BS_ / 4, 256, 0, stream>>>(z1, hbuf, g2 + l * D_, be2 + l * D_, zr, zrb);
  }

  head_kernel<<<BS_ / 4, 256, 0, stream>>>(zr, hw, hb, out);
}

// Round 4
// 615.751 us; speedup vs baseline: 16.4687x; 1.2670x over previous
//
#include <hip/hip_runtime.h>

#define B_   2
#define S_   2048
#define D_   512
#define H_   8
#define DK_  64
#define DFF_ 2048
#define L_   2
#define BS_  (B_*S_)   // 4096
#define NPROJ 2560     // qr|qi|kr|ki|v concatenated

typedef __attribute__((ext_vector_type(8))) short bfrag;    // 8 bf16 (4 VGPRs)
typedef __attribute__((ext_vector_type(4))) float facc;     // 4 fp32
typedef __attribute__((ext_vector_type(16))) float facc16;  // 16 fp32 (32x32 C/D)
typedef __attribute__((ext_vector_type(4))) int i4v;

__device__ __forceinline__ unsigned short f2b(float f) {
  union { float f; unsigned int u; } c; c.f = f;
  unsigned int u = c.u;
  u += 0x7fffu + ((u >> 16) & 1);    // RNE
  return (unsigned short)(u >> 16);
}

__device__ __forceinline__ unsigned pkb(float hi, float lo) {  // truncating bf16 pack
  union { float f; unsigned u; } a, b; a.f = hi; b.f = lo;
  return (a.u & 0xffff0000u) | (b.u >> 16);
}

__device__ __forceinline__ bfrag asb(i4v x) { union { i4v a; bfrag b; } u; u.a = x; return u.b; }

__device__ __forceinline__ bfrag bneg(bfrag x) {
  union { bfrag b; i4v a; } u; u.b = x;
  u.a.x ^= 0x80008000; u.a.y ^= 0x80008000; u.a.z ^= 0x80008000; u.a.w ^= 0x80008000;
  return u.b;
}

__device__ __forceinline__ void async_copy16(const void* g, void* l) {
  __builtin_amdgcn_global_load_lds((const __attribute__((address_space(1))) void*)g,
                                   (__attribute__((address_space(3))) void*)l,
                                   16, 0, 0);
}

// ---------------- embedding gather: zr fp32 + acat bf16 left half ----------------
__global__ __launch_bounds__(128) void embed_kernel(const int* __restrict__ tokens,
                                                    const float* __restrict__ embed,
                                                    float* __restrict__ zr,
                                                    unsigned short* __restrict__ acat) {
  int row = blockIdx.x;
  int tok = tokens[row];
  float4 v = ((const float4*)(embed + (size_t)tok * D_))[threadIdx.x];
  ((float4*)(zr + (size_t)row * D_))[threadIdx.x] = v;
  ushort4 o; o.x = f2b(v.x); o.y = f2b(v.y); o.z = f2b(v.z); o.w = f2b(v.w);
  *(ushort4*)(acat + (size_t)row * 1024 + threadIdx.x * 4) = o;
}

// ---------------- zi bf16 into acat right half ----------------
__global__ __launch_bounds__(128) void zi_kernel(unsigned short* __restrict__ acat) {
  int row = blockIdx.x;
  int s = row & (S_ - 1);
  int d0 = threadIdx.x * 4;
  const double LN1E4 = 9.210340371976184;
  #pragma unroll
  for (int t = 0; t < 4; ++t) {
    int d = d0 + t;
    int jj = d >> 1;
    double freq = exp(-((double)jj / 256.0) * LN1E4);
    float val = (float)sin((double)s * freq);
    acat[(size_t)row * 1024 + 512 + d] = f2b(val);
  }
}

// ---------------- weight concat+transpose for fused projection ----------------
__global__ __launch_bounds__(256) void wcat_kernel(const float* __restrict__ wqr,
                                                   const float* __restrict__ wqi,
                                                   const float* __restrict__ wkr,
                                                   const float* __restrict__ wki,
                                                   const float* __restrict__ wv,
                                                   unsigned short* __restrict__ dst,
                                                   int KA) {
  __shared__ float tile[64][68];
  const int tid = threadIdx.x;
  const int n0 = blockIdx.x * 64, k0 = blockIdx.y * 64;
  const int p = n0 >> 9, nn0 = n0 & 511;
  const float* src;
  float sign = 1.f;
  bool zero = false;
  if (k0 < 512) {
    const float* tops[5] = {wqr, wqi, wkr, wki, wv};
    src = tops[p];
  } else {
    const float* bots[5] = {wqi, wqr, wki, wkr, nullptr};
    const float sg[5] = {-1.f, 1.f, -1.f, 1.f, 0.f};
    src = bots[p]; sign = sg[p]; zero = (p == 4);
  }
  const int kk0 = k0 & 511;
  #pragma unroll
  for (int i = 0; i < 4; ++i) {
    int lin = tid + i * 256;
    int row = lin >> 4, c4 = (lin & 15) * 4;
    float4 v = make_float4(0.f, 0.f, 0.f, 0.f);
    if (!zero) v = *(const float4*)(src + (size_t)(kk0 + row) * 512 + nn0 + c4);
    *(float4*)&tile[row][c4] = v;
  }
  __syncthreads();
  #pragma unroll
  for (int i = 0; i < 4; ++i) {
    int lin = tid + i * 256;
    int n = lin >> 4, kc4 = (lin & 15) * 4;
    ushort4 o;
    o.x = f2b(sign * tile[kc4 + 0][n]);
    o.y = f2b(sign * tile[kc4 + 1][n]);
    o.z = f2b(sign * tile[kc4 + 2][n]);
    o.w = f2b(sign * tile[kc4 + 3][n]);
    *(ushort4*)(dst + (size_t)(n0 + n) * KA + k0 + kc4) = o;
  }
}

// ---------------- generic weight transpose: fp32 [K,N] -> bf16 [N,K] ----------------
__global__ __launch_bounds__(256) void wtr_kernel(const float* __restrict__ W,
                                                  unsigned short* __restrict__ dst,
                                                  int K, int N) {
  __shared__ float tile[64][68];
  const int tid = threadIdx.x;
  const int n0 = blockIdx.x * 64, k0 = blockIdx.y * 64;
  #pragma unroll
  for (int i = 0; i < 4; ++i) {
    int lin = tid + i * 256;
    int row = lin >> 4, c4 = (lin & 15) * 4;
    *(float4*)&tile[row][c4] = *(const float4*)(W + (size_t)(k0 + row) * N + n0 + c4);
  }
  __syncthreads();
  #pragma unroll
  for (int i = 0; i < 4; ++i) {
    int lin = tid + i * 256;
    int n = lin >> 4, kc4 = (lin & 15) * 4;
    ushort4 o;
    o.x = f2b(tile[kc4 + 0][n]);
    o.y = f2b(tile[kc4 + 1][n]);
    o.z = f2b(tile[kc4 + 2][n]);
    o.w = f2b(tile[kc4 + 3][n]);
    *(ushort4*)(dst + (size_t)(n0 + n) * K + k0 + kc4) = o;
  }
}

// ---------------- bf16 MFMA GEMM (m97 pattern) ----------------
template<int TM>
__global__ __launch_bounds__(256) void gemm_bf16(const unsigned short* __restrict__ A,
                                                 const unsigned short* __restrict__ Bt,
                                                 const float* __restrict__ bias,
                                                 float* __restrict__ outF,
                                                 unsigned short* __restrict__ outB,
                                                 int M, int N, int K, int lda, int relu) {
  constexpr int MT = TM / 32;
  __shared__ short smem[(TM + 128) * 32];
  short* A_s = smem;
  short* B_s = smem + TM * 32;

  const int tid = threadIdx.x;
  const int w = tid >> 6, lane = tid & 63;
  const int col = lane & 15, quad = lane >> 4;
  const int m0 = blockIdx.y * TM, n0 = blockIdx.x * 128;
  const int wrow = (w >> 1) * (TM / 2);
  const int wcol = (w & 1) * 64;

  const int srow = lane >> 2;
  const int skk  = (lane & 3) * 8;

  facc acc[MT][4];
  #pragma unroll
  for (int i = 0; i < MT; ++i)
    #pragma unroll
    for (int j = 0; j < 4; ++j) acc[i][j] = (facc){0.f, 0.f, 0.f, 0.f};

  for (int k0 = 0; k0 < K; k0 += 32) {
    __syncthreads();
    #pragma unroll
    for (int rd = 0; rd < TM / 64; ++rd) {
      int row = rd * 64 + w * 16 + srow;
      async_copy16(A + (size_t)(m0 + row) * lda + k0 + skk, &A_s[row * 32 + skk]);
    }
    #pragma unroll
    for (int rd = 0; rd < 2; ++rd) {
      int row = rd * 64 + w * 16 + srow;
      async_copy16(Bt + (size_t)(n0 + row) * K + k0 + skk, &B_s[row * 32 + skk]);
    }
    __syncthreads();

    bfrag af[MT], bf[4];
    #pragma unroll
    for (int i = 0; i < MT; ++i)
      af[i] = *(const bfrag*)&A_s[(wrow + i * 16 + col) * 32 + quad * 8];
    #pragma unroll
    for (int j = 0; j < 4; ++j)
      bf[j] = *(const bfrag*)&B_s[(wcol + j * 16 + col) * 32 + quad * 8];
    #pragma unroll
    for (int i = 0; i < MT; ++i)
      #pragma unroll
      for (int j = 0; j < 4; ++j)
        acc[i][j] = __builtin_amdgcn_mfma_f32_16x16x32_bf16(af[i], bf[j], acc[i][j], 0, 0, 0);
  }

  #pragma unroll
  for (int i = 0; i < MT; ++i) {
    #pragma unroll
    for (int j = 0; j < 4; ++j) {
      int colIdx = n0 + wcol + j * 16 + col;
      float b = bias ? bias[colIdx] : 0.f;
      #pragma unroll
      for (int r = 0; r < 4; ++r) {
        int rowIdx = m0 + wrow + i * 16 + quad * 4 + r;
        float v = acc[i][j][r] + b;
        if (relu) v = fmaxf(v, 0.f);
        if (outF) outF[(size_t)rowIdx * N + colIdx] = v;
        if (outB) outB[(size_t)rowIdx * N + colIdx] = f2b(v);
      }
    }
  }
}

// ---------------- V transpose: Q4 cols [2048,2560) -> bf16 [b,h,dk,s] ----------------
__global__ __launch_bounds__(256) void vt_kernel(const unsigned short* __restrict__ Q4,
                                                 unsigned short* __restrict__ vt) {
  __shared__ short tile[64][80];
  const int bh = blockIdx.x;
  const int b = bh >> 3, hd = bh & 7;
  const int s0 = blockIdx.y * 64;
  const int tid = threadIdx.x;
  #pragma unroll
  for (int i = 0; i < 2; ++i) {
    int lin = tid + i * 256;
    int row = lin >> 3;
    int c8 = (lin & 7) * 8;
    *(int4*)&tile[row][c8] =
      *(const int4*)(Q4 + (size_t)(b * S_ + s0 + row) * NPROJ + 2048 + hd * DK_ + c8);
  }
  __syncthreads();
  #pragma unroll
  for (int i = 0; i < 2; ++i) {
    int lin = tid + i * 256;
    int d = lin >> 3;
    int s8 = (lin & 7) * 8;
    short tmp[8];
    #pragma unroll
    for (int t = 0; t < 8; ++t) tmp[t] = tile[s8 + t][d];
    *(int4*)(vt + ((size_t)bh * DK_ + d) * S_ + s0 + s8) = *(const int4*)tmp;
  }
}

// ---------------- MFMA complex-hybrid attention, v2 ----------------
// 32x32x16 MFMA, A=K B=Q (C col = q). Fixed softmax max m=0 (scores tiny).
// grid (S/32, B*H); block 256 = 4 waves; wave w owns keys [w*512, w*512+512),
// all waves share the block's 32 q rows. Per-wave-private LDS staging, no
// barriers in the main loop; partial (o,l) combined across waves at the end.
__global__ __launch_bounds__(256, 3) void attn_mfma(const unsigned short* __restrict__ Q4,
                                                    const unsigned short* __restrict__ VT,
                                                    unsigned short* __restrict__ CTXB) {
  __shared__ __align__(16) char smem[49152];

  const int bh = blockIdx.y;
  const int b = bh >> 3, hd = bh & 7;
  const int hoff = hd * DK_;
  const int q0 = blockIdx.x * 32;
  const int tid = threadIdx.x;
  const int w = tid >> 6;
  const int lane = tid & 63;
  const int m = lane & 31;       // C col = q index / A m index
  const int h = lane >> 5;       // half-wave
  const int x7 = m & 7;

  short* kr_s = (short*)(smem + w * 12288);
  short* ki_s = kr_s + 2048;
  short* vt_s = ki_s + 2048;

  const size_t bS = (size_t)b * S_;
  const size_t vtbase = (size_t)bh * DK_ * S_;

  // Q B-frags (persistent): B[kdim = t*16 + h*8 + j][n=q=m]
  bfrag qrf[4], qif[4], nqrf[4];
  {
    const size_t qrow = (bS + q0 + m) * (size_t)NPROJ + hoff;
    #pragma unroll
    for (int t = 0; t < 4; ++t) {
      qrf[t] = *(const bfrag*)(Q4 + qrow + t * 16 + h * 8);
      qif[t] = *(const bfrag*)(Q4 + qrow + 512 + t * 16 + h * 8);
      nqrf[t] = bneg(qrf[t]);
    }
  }

  // staging lambdas (async global->LDS, dest = base + lane*16)
  auto stage_k = [&](int c0) {
    #pragma unroll
    for (int it = 0; it < 4; ++it) {
      int slot = it * 64 + lane;
      int key = slot >> 3;
      int ls = (slot & 7) ^ (key & 7);            // XOR bank swizzle
      const unsigned short* gk = Q4 + (bS + c0 + key) * (size_t)NPROJ + hoff + ls * 8;
      async_copy16(gk + 1024, (char*)kr_s + slot * 16);
      async_copy16(gk + 1536, (char*)ki_s + slot * 16);
    }
  };
  auto stage_v = [&](int c0) {
    #pragma unroll
    for (int it = 0; it < 4; ++it) {
      int slot = it * 64 + lane;
      int d = slot >> 2;
      int ls = (slot & 3) ^ (d & 3);              // XOR bank swizzle
      async_copy16(VT + vtbase + (size_t)d * S_ + c0 + ls * 8, (char*)vt_s + slot * 16);
    }
  };

  facc16 o0 = {}, o1 = {};
  float l = 0.f;
  const float c1 = 0.022542110f;   // (1/64)*log2e
  const float c2 = 0.054101064f;   // 0.0375*log2e

  const int kbase = w * 512;
  stage_k(kbase);
  stage_v(kbase);

  for (int ch = 0; ch < 16; ++ch) {
    const int c0n = kbase + (ch + 1) * 32;
    __builtin_amdgcn_s_waitcnt(0x0F70);          // vmcnt(0): staging landed

    // ---- K frags (A-operand): A[m=key][kdim = t*16+h*8+j] ----
    bfrag krf[4], kif[4];
    #pragma unroll
    for (int t = 0; t < 4; ++t) {
      int off = m * 128 + (((2 * t + h) ^ x7) << 4);
      krf[t] = *(const bfrag*)((const char*)kr_s + off);
      kif[t] = *(const bfrag*)((const char*)ki_s + off);
    }
    __builtin_amdgcn_s_waitcnt(0xC07F);          // lgkmcnt(0): frags in regs
    if (ch < 15) stage_k(c0n);

    // ---- scores ----
    facc16 sr = {}, si = {};
    #pragma unroll
    for (int t = 0; t < 4; ++t) {
      sr = __builtin_amdgcn_mfma_f32_32x32x16_bf16(krf[t], qrf[t], sr, 0, 0, 0);
      si = __builtin_amdgcn_mfma_f32_32x32x16_bf16(krf[t], qif[t], si, 0, 0, 0);
      sr = __builtin_amdgcn_mfma_f32_32x32x16_bf16(kif[t], qif[t], sr, 0, 0, 0);
      si = __builtin_amdgcn_mfma_f32_32x32x16_bf16(kif[t], nqrf[t], si, 0, 0, 0);
    }

    // ---- hybrid score -> p = exp2(log2e*score), fixed m=0 ----
    float p[16], ssum = 0.f;
    #pragma unroll
    for (int i = 0; i < 16; ++i) {
      float a = sr[i], bb = si[i];
      float d2 = __builtin_fmaf(a, a, __builtin_fmaf(bb, bb, 1e-30f));
      float rs = rsqrtf(d2);
      float tt = __builtin_fmaf(c1, d2, c2 * a);
      p[i] = exp2f(rs * tt);
      ssum += p[i];
    }
    l += ssum;

    // ---- pack P (truncating bf16) + cross-half exchange -> P^T B-frags ----
    unsigned dw[8];
    #pragma unroll
    for (int i = 0; i < 8; ++i) dw[i] = pkb(p[2 * i + 1], p[2 * i]);
    unsigned y1 = (unsigned)__shfl_xor((int)(h ? dw[0] : dw[2]), 32);
    unsigned y2 = (unsigned)__shfl_xor((int)(h ? dw[1] : dw[3]), 32);
    unsigned y3 = (unsigned)__shfl_xor((int)(h ? dw[4] : dw[6]), 32);
    unsigned y4 = (unsigned)__shfl_xor((int)(h ? dw[5] : dw[7]), 32);
    i4v f0 = { (int)(h ? y1 : dw[0]), (int)(h ? y2 : dw[1]),
               (int)(h ? dw[2] : y1), (int)(h ? dw[3] : y2) };
    i4v f1 = { (int)(h ? y3 : dw[4]), (int)(h ? y4 : dw[5]),
               (int)(h ? dw[6] : y3), (int)(h ? dw[7] : y4) };
    bfrag pf0 = asb(f0), pf1 = asb(f1);

    // ---- V^T frags (A-operand): A[m=d][kdim = kt*16+h*8+j] ----
    bfrag vtf[4];
    #pragma unroll
    for (int tile = 0; tile < 2; ++tile)
      #pragma unroll
      for (int kt = 0; kt < 2; ++kt)
        vtf[tile * 2 + kt] = *(const bfrag*)((const char*)vt_s +
            (tile * 32 + m) * 64 + (((kt * 2 + h) ^ (m & 3)) << 4));
    __builtin_amdgcn_s_waitcnt(0xC07F);          // lgkmcnt(0)
    if (ch < 15) stage_v(c0n);

    // ---- PV: o^T[d][q] += V^T x P^T ----
    o0 = __builtin_amdgcn_mfma_f32_32x32x16_bf16(vtf[0], pf0, o0, 0, 0, 0);
    o0 = __builtin_amdgcn_mfma_f32_32x32x16_bf16(vtf[1], pf1, o0, 0, 0, 0);
    o1 = __builtin_amdgcn_mfma_f32_32x32x16_bf16(vtf[2], pf0, o1, 0, 0, 0);
    o1 = __builtin_amdgcn_mfma_f32_32x32x16_bf16(vtf[3], pf1, o1, 0, 0, 0);
  }

  // ---- combine partials across waves ----
  float l_tot = l + __shfl_xor(l, 32);
  __syncthreads();
  float* cw = (float*)smem;                       // [4][32][68]
  float* lw = (float*)(smem + 34816);             // [4][32]
  #pragma unroll
  for (int tile = 0; tile < 2; ++tile) {
    const facc16& oo = tile ? o1 : o0;
    #pragma unroll
    for (int rg = 0; rg < 4; ++rg) {
      int d0 = tile * 32 + rg * 8 + h * 4;        // d = (reg&3)+8*(reg>>2)+4h
      float4 vv = make_float4(oo[4 * rg], oo[4 * rg + 1], oo[4 * rg + 2], oo[4 * rg + 3]);
      *(float4*)&cw[w * 2176 + m * 68 + d0] = vv;
    }
  }
  if (lane < 32) lw[w * 32 + m] = l_tot;
  __syncthreads();

  {
    int q = tid >> 3, dg = tid & 7;
    float acc8[8];
    #pragma unroll
    for (int e = 0; e < 8; ++e) acc8[e] = 0.f;
    float lsum = 0.f;
    #pragma unroll
    for (int wv = 0; wv < 4; ++wv) {
      const float* src = &cw[wv * 2176 + q * 68 + dg * 8];
      #pragma unroll
      for (int e = 0; e < 8; ++e) acc8[e] += src[e];
      lsum += lw[wv * 32 + q];
    }
    float inv = 1.f / lsum;
    unsigned short ob[8];
    #pragma unroll
    for (int e = 0; e < 8; ++e) ob[e] = f2b(acc8[e] * inv);
    *(int4*)(CTXB + (size_t)(b * S_ + q0 + q) * D_ + hoff + dg * 8) = *(const int4*)ob;
  }
}

// ---------------- layernorm ----------------
__global__ __launch_bounds__(256) void ln_kernel(const float* __restrict__ X,
                                                 const float* __restrict__ R,
                                                 const float* __restrict__ g,
                                                 const float* __restrict__ be,
                                                 float* __restrict__ OutF,
                                                 unsigned short* __restrict__ OutB) {
  const int lane = threadIdx.x & 63;
  const int wv = threadIdx.x >> 6;
  const int row = blockIdx.x * 4 + wv;
  const float* xp = X + (size_t)row * D_;
  const float* rp = R + (size_t)row * D_;
  float x[8];
  float s = 0.f;
  #pragma unroll
  for (int i = 0; i < 8; ++i) {
    int d = i * 64 + lane;
    x[i] = xp[d] + rp[d];
    s += x[i];
  }
  s += __shfl_xor(s, 32); s += __shfl_xor(s, 16); s += __shfl_xor(s, 8);
  s += __shfl_xor(s, 4);  s += __shfl_xor(s, 2);  s += __shfl_xor(s, 1);
  float mu = s * (1.f / 512.f);
  float vs = 0.f;
  #pragma unroll
  for (int i = 0; i < 8; ++i) { float d = x[i] - mu; vs += d * d; }
  vs += __shfl_xor(vs, 32); vs += __shfl_xor(vs, 16); vs += __shfl_xor(vs, 8);
  vs += __shfl_xor(vs, 4);  vs += __shfl_xor(vs, 2);  vs += __shfl_xor(vs, 1);
  float rstd = rsqrtf(vs * (1.f / 512.f) + 1e-5f);
  #pragma unroll
  for (int i = 0; i < 8; ++i) {
    int d = i * 64 + lane;
    float v = (x[i] - mu) * rstd * g[d] + be[d];
    if (OutF) OutF[(size_t)row * D_ + d] = v;
    if (OutB) OutB[(size_t)row * D_ + d] = f2b(v);
  }
}

// ---------------- classifier head ----------------
__global__ __launch_bounds__(256) void head_kernel(const float* __restrict__ Z,
                                                   const float* __restrict__ hw,
                                                   const float* __restrict__ hb,
                                                   float* __restrict__ out) {
  const int lane = threadIdx.x & 63;
  const int wv = threadIdx.x >> 6;
  const int row = blockIdx.x * 4 + wv;
  const float* zp = Z + (size_t)row * D_;
  float a0 = 0.f, a1 = 0.f;
  #pragma unroll
  for (int i = 0; i < 8; ++i) {
    int d = i * 64 + lane;
    float z = zp[d];
    a0 += z * hw[d * 2];
    a1 += z * hw[d * 2 + 1];
  }
  a0 += __shfl_xor(a0, 32); a0 += __shfl_xor(a0, 16); a0 += __shfl_xor(a0, 8);
  a0 += __shfl_xor(a0, 4);  a0 += __shfl_xor(a0, 2);  a0 += __shfl_xor(a0, 1);
  a1 += __shfl_xor(a1, 32); a1 += __shfl_xor(a1, 16); a1 += __shfl_xor(a1, 8);
  a1 += __shfl_xor(a1, 4);  a1 += __shfl_xor(a1, 2);  a1 += __shfl_xor(a1, 1);
  if (lane == 0) {
    out[row * 2]     = a0 + hb[0];
    out[row * 2 + 1] = a1 + hb[1];
  }
}

extern "C" void kernel_launch(void* const* d_in, const int* in_sizes, int n_in,
                              void* d_out, int out_size, void* d_ws, size_t ws_size,
                              hipStream_t stream) {
  const int*   tokens = (const int*)  d_in[0];
  const float* embed  = (const float*)d_in[1];
  const float* Wqr = (const float*)d_in[2];
  const float* Wqi = (const float*)d_in[3];
  const float* Wkr = (const float*)d_in[4];
  const float* Wki = (const float*)d_in[5];
  const float* Wv  = (const float*)d_in[6];
  const float* Wo  = (const float*)d_in[7];
  const float* bo  = (const float*)d_in[8];
  const float* W1  = (const float*)d_in[9];
  const float* b1  = (const float*)d_in[10];
  const float* W2  = (const float*)d_in[11];
  const float* b2  = (const float*)d_in[12];
  const float* g1  = (const float*)d_in[13];
  const float* be1 = (const float*)d_in[14];
  const float* g2  = (const float*)d_in[15];
  const float* be2 = (const float*)d_in[16];
  const float* hw  = (const float*)d_in[17];
  const float* hb  = (const float*)d_in[18];
  float* out = (float*)d_out;

  char* p = (char*)d_ws;
  float* zr = (float*)p;             p += (size_t)BS_ * D_ * 4;
  unsigned short* acat = (unsigned short*)p;
  unsigned short* zrb  = acat;       p += (size_t)BS_ * 1024 * 2;
  unsigned short* Q4   = (unsigned short*)p;
  unsigned short* ffb  = Q4;         p += (size_t)BS_ * NPROJ * 2;
  unsigned short* VT   = (unsigned short*)p; p += (size_t)B_*H_*DK_*S_*2;
  unsigned short* ctxb = (unsigned short*)p; p += (size_t)BS_ * D_ * 2;
  float* hbuf = (float*)p;           p += (size_t)BS_ * D_ * 4;
  float* z1   = (float*)p;           p += (size_t)BS_ * D_ * 4;
  unsigned short* z1b = (unsigned short*)p;  p += (size_t)BS_ * D_ * 2;
  unsigned short* wsc = (unsigned short*)p;  p += (size_t)NPROJ * 1024 * 2;

  embed_kernel<<<BS_, 128, 0, stream>>>(tokens, embed, zr, acat);
  zi_kernel<<<BS_, 128, 0, stream>>>(acat);

  for (int l = 0; l < L_; ++l) {
    const float* wqr = Wqr + (size_t)l * D_ * D_;
    const float* wqi = Wqi + (size_t)l * D_ * D_;
    const float* wkr = Wkr + (size_t)l * D_ * D_;
    const float* wki = Wki + (size_t)l * D_ * D_;
    const float* wv  = Wv  + (size_t)l * D_ * D_;
    const float* wo  = Wo  + (size_t)l * D_ * D_;
    const float* w1  = W1  + (size_t)l * D_ * DFF_;
    const float* w2  = W2  + (size_t)l * DFF_ * D_;

    const int KA = (l == 0) ? 1024 : 512;
    const unsigned short* Aproj = (l == 0) ? acat : zrb;

    wcat_kernel<<<dim3(NPROJ / 64, KA / 64), 256, 0, stream>>>(wqr, wqi, wkr, wki, wv, wsc, KA);
    gemm_bf16<128><<<dim3(NPROJ / 128, BS_ / 128), 256, 0, stream>>>(
        Aproj, wsc, nullptr, nullptr, Q4, BS_, NPROJ, KA, KA, 0);

    vt_kernel<<<dim3(B_ * H_, S_ / 64), 256, 0, stream>>>(Q4, VT);
    attn_mfma<<<dim3(S_ / 32, B_ * H_), 256, 0, stream>>>(Q4, VT, ctxb);

    wtr_kernel<<<dim3(D_ / 64, D_ / 64), 256, 0, stream>>>(wo, wsc, D_, D_);
    gemm_bf16<64><<<dim3(D_ / 128, BS_ / 64), 256, 0, stream>>>(
        ctxb, wsc, bo + l * D_, hbuf, nullptr, BS_, D_, D_, D_, 0);
    ln_kernel<<<BS_ / 4, 256, 0, stream>>>(zr, hbuf, g1 + l * D_, be1 + l * D_, z1, z1b);

    wtr_kernel<<<dim3(DFF_ / 64, D_ / 64), 256, 0, stream>>>(w1, wsc, D_, DFF_);
    gemm_bf16<128><<<dim3(DFF_ / 128, BS_ / 128), 256, 0, stream>>>(
        z1b, wsc, b1 + l * DFF_, nullptr, ffb, BS_, DFF_, D_, D_, 1);
    wtr_kernel<<<dim3(D_ / 64, DFF_ / 64), 256, 0, stream>>>(w2, wsc, DFF_, D_);
    gemm_bf16<64><<<dim3(D_ / 128, BS_ / 64), 256, 0, stream>>>(
        ffb, wsc, b2 + l * D_, hbuf, nullptr, BS_, D_, DFF_, DFF_, 0);
    ln_kernel<<<BS_ / 4, 256, 0, stream>>>(z1, hbuf, g2 + l * D_, be2 + l * D_, zr, zrb);
  }

  head_kernel<<<BS_ / 4, 256, 0, stream>>>(zr, hw, hb, out);
}